// Round 2
// baseline (538.349 us; speedup 1.0000x reference)
//
#include <hip/hip_runtime.h>
#include <math.h>

#define LQ_ 5440
#define NB_ 8
#define NQ_ (NB_ * LQ_)   // 43520
#define D_  256
#define NH_ 8
#define HD_ 32

typedef __attribute__((ext_vector_type(8))) short short8;
typedef __attribute__((ext_vector_type(4))) float f32x4;

__device__ __forceinline__ ushort f2bf(float f) {
    union { float f; unsigned u; } v; v.f = f;
    unsigned u = v.u;
    unsigned r = (u + 0x7FFFu + ((u >> 16) & 1u)) >> 16;
    return (ushort)r;
}

// async global->LDS, 16 B per lane. LDS dest = wave-uniform base + lane*16.
__device__ __forceinline__ void gload_lds16(const void* g, void* l) {
    __builtin_amdgcn_global_load_lds(
        (const __attribute__((address_space(1))) void*)g,
        (__attribute__((address_space(3))) void*)l, 16, 0, 0);
}

// ---------------------------------------------------------------------------
// Input prep: s_bf = bf16(src), q_bf = bf16(src+pos). 4 elems/thread.
// ---------------------------------------------------------------------------
__global__ void make_bf_inputs(const float* __restrict__ src, const float* __restrict__ pos,
                               ushort* __restrict__ s_bf, ushort* __restrict__ q_bf) {
    const int i = blockIdx.x * blockDim.x + threadIdx.x;
    const float4 s = ((const float4*)src)[i];
    const float4 p = ((const float4*)pos)[i];
    ushort4 a, b;
    a.x = f2bf(s.x); a.y = f2bf(s.y); a.z = f2bf(s.z); a.w = f2bf(s.w);
    b.x = f2bf(s.x + p.x); b.y = f2bf(s.y + p.y); b.z = f2bf(s.z + p.z); b.w = f2bf(s.w + p.w);
    ((ushort4*)s_bf)[i] = a;
    ((ushort4*)q_bf)[i] = b;
}

// ---------------------------------------------------------------------------
// Weight transpose + bf16 cast: W [K,N] fp32 -> Wt [N,K] bf16.
// ---------------------------------------------------------------------------
__global__ void transpose_w(const float* __restrict__ W, ushort* __restrict__ Wt, int K, int N) {
    __shared__ float tile[32][33];
    const int bx = blockIdx.x;   // n tile
    const int by = blockIdx.y;   // k tile
    const int tx = threadIdx.x;  // 0..31
    const int ty = threadIdx.y;  // 0..7
    for (int i = ty; i < 32; i += 8)
        tile[i][tx] = W[(size_t)(by * 32 + i) * N + bx * 32 + tx];
    __syncthreads();
    for (int i = ty; i < 32; i += 8)
        Wt[(size_t)(bx * 32 + i) * K + by * 32 + tx] = f2bf(tile[tx][i]);
}

// ---------------------------------------------------------------------------
// MFMA GEMM: C[M,N] = A[M,K](bf16) @ Bt[N,K](bf16)^T + bias, opt ReLU.
// 128x128 tile, BK=64, 4 waves, 4x4 16x16x32 tiles/wave.
// Double-buffered 2-phase loop (T3-minimum): stage(k+1) issued BEFORE
// compute(k), ONE barrier per K-iter (was 2). global_load_lds width-16,
// linear LDS. grid = (N/BN, M/BM) so neighboring blocks share the A panel.
// ---------------------------------------------------------------------------
#define BM 128
#define BN 128
#define BK 64

__global__ __launch_bounds__(256)
void mfma_gemm(const ushort* __restrict__ A, const ushort* __restrict__ Bt,
               const float* __restrict__ bias, float* __restrict__ Cf,
               ushort* __restrict__ Cb, int N, int K, int relu) {
    __shared__ ushort lA[2][BM * BK];   // 2 x 16 KiB
    __shared__ ushort lB[2][BN * BK];   // 2 x 16 KiB
    const int t    = threadIdx.x;
    const int col0 = blockIdx.x * BN;
    const int row0 = blockIdx.y * BM;
    const int w    = t >> 6;
    const int lr   = t & 15;
    const int quad = (t >> 4) & 3;
    const int wm   = (w >> 1) * 64;
    const int wn   = (w & 1) * 64;

    f32x4 acc[4][4];
    #pragma unroll
    for (int i = 0; i < 4; ++i)
        #pragma unroll
        for (int j = 0; j < 4; ++j)
            acc[i][j] = (f32x4){0.f, 0.f, 0.f, 0.f};

    // staging geometry: lane t covers row (t>>3)+32g, elems (t&7)*8..+7
    // -> LDS byte t*16 + g*4096 == wave base (w*1024 + g*4096) + lane*16.
    const int sr = t >> 3;
    const int sc = (t & 7) * 8;
    const size_t aoff = (size_t)(row0 + sr) * K + sc;
    const size_t boff = (size_t)(col0 + sr) * K + sc;
    const int wb = w * 1024;

    auto stage = [&](int buf, int k0) {
        char* la = (char*)lA[buf] + wb;
        char* lb = (char*)lB[buf] + wb;
        #pragma unroll
        for (int g = 0; g < 4; ++g) {
            gload_lds16(A  + aoff + k0 + (size_t)g * 32 * K, la + g * 4096);
            gload_lds16(Bt + boff + k0 + (size_t)g * 32 * K, lb + g * 4096);
        }
    };

    stage(0, 0);
    __syncthreads();               // drains vmcnt(0): buf0 ready
    int cur = 0;
    for (int k0 = 0; k0 < K; k0 += BK) {
        if (k0 + BK < K) stage(cur ^ 1, k0 + BK);   // prefetch next tile
        const ushort* pA = lA[cur];
        const ushort* pB = lB[cur];
        #pragma unroll
        for (int kk = 0; kk < 2; ++kk) {
            short8 af[4], bfr[4];
            #pragma unroll
            for (int i = 0; i < 4; ++i)
                af[i] = *(const short8*)(pA + (wm + i * 16 + lr) * BK + kk * 32 + quad * 8);
            #pragma unroll
            for (int j = 0; j < 4; ++j)
                bfr[j] = *(const short8*)(pB + (wn + j * 16 + lr) * BK + kk * 32 + quad * 8);
            #pragma unroll
            for (int i = 0; i < 4; ++i)
                #pragma unroll
                for (int j = 0; j < 4; ++j)
                    acc[i][j] = __builtin_amdgcn_mfma_f32_16x16x32_bf16(af[i], bfr[j], acc[i][j], 0, 0, 0);
        }
        __syncthreads();           // prefetch drained + all reads of cur done
        cur ^= 1;
    }

    #pragma unroll
    for (int j = 0; j < 4; ++j) {
        const int col = col0 + wn + j * 16 + lr;
        const float bb = bias ? bias[col] : 0.f;
        #pragma unroll
        for (int i = 0; i < 4; ++i) {
            const int rbase = row0 + wm + i * 16 + quad * 4;
            #pragma unroll
            for (int r = 0; r < 4; ++r) {
                float v = acc[i][j][r] + bb;
                if (relu) v = fmaxf(v, 0.f);
                if (Cf) Cf[(size_t)(rbase + r) * N + col] = v;
                else    Cb[(size_t)(rbase + r) * N + col] = f2bf(v);
            }
        }
    }
}

// ---------------------------------------------------------------------------
// Fused softmax + deformable bilinear sampling.
// Block = 256 threads, 8 queries/block.
// Phase 1 (x4 iterations): thread handles one (q,h,p): softmax (shfl over the
//   16-point group, lane-local), 4 corner BYTE offsets + 4 folded weights->LDS.
// Phase 2: thread = (q, h, dq): dq selects a 16 B (8-elem) slice of the head
//   row. 64 corners x 1 global dwordx4 each. VMEM/addressing insts are 1/4 of
//   the dword version; FMA count unchanged (VALU-bound kernel).
// ---------------------------------------------------------------------------
#define QPB 8

__global__ __launch_bounds__(256)
void msda_sample(const ushort* __restrict__ value, const float* __restrict__ comb,
                 const float* __restrict__ b_off, const float* __restrict__ b_attn,
                 const float* __restrict__ refp, ushort* __restrict__ out) {
    __shared__ int   s_addr[QPB * 128][4];   // byte offsets into value (16 KiB)
    __shared__ float s_w[QPB * 128][4];      // folded weights (16 KiB)

    const int t = threadIdx.x;

    // ---------------- phase 1: (q,h,p), 4 slots/thread ----------------
    #pragma unroll
    for (int it = 0; it < 4; ++it) {
        const int q_local = it * 2 + (t >> 7);
        const int u  = t & 127;
        const int nq = blockIdx.x * QPB + q_local;
        const int n  = nq / LQ_;
        const int p  = u & 15;
        const int l  = p >> 2;

        const int starts[4] = {0, 4096, 5120, 5376};
        const int Wl = 64 >> l;

        // softmax over 16 points (p = low 4 lane bits -> shfl_xor group)
        float a = comb[(size_t)nq * 384 + 256 + u] + b_attn[u];
        float m = a;
        #pragma unroll
        for (int o = 8; o > 0; o >>= 1) m = fmaxf(m, __shfl_xor(m, o));
        float e = __expf(a - m);
        float s = e;
        #pragma unroll
        for (int o = 8; o > 0; o >>= 1) s += __shfl_xor(s, o);
        const float wgt = e / s;

        const float rx = refp[(size_t)nq * 8 + l * 2 + 0];
        const float ry = refp[(size_t)nq * 8 + l * 2 + 1];
        const float ox = comb[(size_t)nq * 384 + u * 2 + 0] + b_off[u * 2 + 0];
        const float oy = comb[(size_t)nq * 384 + u * 2 + 1] + b_off[u * 2 + 1];

        const float fw = (float)Wl;
        const float x  = (rx + ox / fw) * fw - 0.5f;
        const float y  = (ry + oy / fw) * fw - 0.5f;
        const float x0f = floorf(x), y0f = floorf(y);
        const int   x0 = (int)x0f, y0 = (int)y0f;
        const float wx1 = x - x0f, wy1 = y - y0f;
        const float wx0 = 1.f - wx1, wy0 = 1.f - wy1;

        const float xm0 = (x0 >= 0 && x0 < Wl) ? 1.f : 0.f;
        const float xm1 = (x0 + 1 >= 0 && x0 + 1 < Wl) ? 1.f : 0.f;
        const float ym0 = (y0 >= 0 && y0 < Wl) ? 1.f : 0.f;
        const float ym1 = (y0 + 1 >= 0 && y0 + 1 < Wl) ? 1.f : 0.f;

        const int x0c = min(max(x0, 0), Wl - 1);
        const int x1c = min(max(x0 + 1, 0), Wl - 1);
        const int y0c = min(max(y0, 0), Wl - 1);
        const int y1c = min(max(y0 + 1, 0), Wl - 1);

        // BYTE offsets: value row = 256 bf16 = 512 B; head offset = h*64 B
        const int h    = u >> 4;
        const int base = (n * LQ_ + starts[l]) * 512 + h * 64;
        const int idx  = q_local * 128 + u;
        s_addr[idx][0] = base + (y0c * Wl + x0c) * 512;
        s_addr[idx][1] = base + (y0c * Wl + x1c) * 512;
        s_addr[idx][2] = base + (y1c * Wl + x0c) * 512;
        s_addr[idx][3] = base + (y1c * Wl + x1c) * 512;
        s_w[idx][0] = wgt * wy0 * wx0 * ym0 * xm0;
        s_w[idx][1] = wgt * wy0 * wx1 * ym0 * xm1;
        s_w[idx][2] = wgt * wy1 * wx0 * ym1 * xm0;
        s_w[idx][3] = wgt * wy1 * wx1 * ym1 * xm1;
    }
    __syncthreads();

    // ---------------- phase 2: (q,h,dq) ----------------
    {
        const int q_local = t >> 5;
        const int h   = (t >> 2) & 7;
        const int dq  = t & 3;                    // 16 B slice of the 64 B head row
        const int nq  = blockIdx.x * QPB + q_local;
        const int sb  = q_local * 128 + h * 16;
        const uint dby = (uint)(dq * 16);
        const char* vbase = (const char*)value;

        float acc[8] = {0.f, 0.f, 0.f, 0.f, 0.f, 0.f, 0.f, 0.f};
        #pragma unroll 4
        for (int p = 0; p < 16; ++p) {
            const int*   ap = s_addr[sb + p];
            const float* wp = s_w[sb + p];
            #pragma unroll
            for (int c = 0; c < 4; ++c) {
                const uint4 v = *(const uint4*)(vbase + ((uint)ap[c] + dby));
                const float w = wp[c];
                union { uint u; float f; } b0;
                b0.u = v.x << 16;          acc[0] = fmaf(b0.f, w, acc[0]);
                b0.u = v.x & 0xffff0000u;  acc[1] = fmaf(b0.f, w, acc[1]);
                b0.u = v.y << 16;          acc[2] = fmaf(b0.f, w, acc[2]);
                b0.u = v.y & 0xffff0000u;  acc[3] = fmaf(b0.f, w, acc[3]);
                b0.u = v.z << 16;          acc[4] = fmaf(b0.f, w, acc[4]);
                b0.u = v.z & 0xffff0000u;  acc[5] = fmaf(b0.f, w, acc[5]);
                b0.u = v.w << 16;          acc[6] = fmaf(b0.f, w, acc[6]);
                b0.u = v.w & 0xffff0000u;  acc[7] = fmaf(b0.f, w, acc[7]);
            }
        }
        uint4 o;
        o.x = (uint)f2bf(acc[0]) | ((uint)f2bf(acc[1]) << 16);
        o.y = (uint)f2bf(acc[2]) | ((uint)f2bf(acc[3]) << 16);
        o.z = (uint)f2bf(acc[4]) | ((uint)f2bf(acc[5]) << 16);
        o.w = (uint)f2bf(acc[6]) | ((uint)f2bf(acc[7]) << 16);
        *(uint4*)(out + (size_t)nq * 256 + h * 32 + dq * 8) = o;
    }
}

// ---------------------------------------------------------------------------
// x = LayerNorm(a + b); wave-per-row, float4 per lane, shuffle-only reduce.
// grid = NQ/4, block = 256 (4 waves = 4 rows).
// ---------------------------------------------------------------------------
__global__ __launch_bounds__(256)
void add_ln(const float* __restrict__ a, const float* __restrict__ b,
            const float* __restrict__ g, const float* __restrict__ be,
            float* __restrict__ xf, ushort* __restrict__ xb) {
    const int row  = blockIdx.x * 4 + (threadIdx.x >> 6);
    const int lane = threadIdx.x & 63;
    const size_t base = (size_t)row * 256 + lane * 4;

    const float4 av = *(const float4*)(a + base);
    const float4 bv = *(const float4*)(b + base);
    float4 x;
    x.x = av.x + bv.x; x.y = av.y + bv.y; x.z = av.z + bv.z; x.w = av.w + bv.w;

    float s = x.x + x.y + x.z + x.w;
    #pragma unroll
    for (int o = 32; o > 0; o >>= 1) s += __shfl_xor(s, o);
    const float mu = s * (1.f / 256.f);

    float4 dx;
    dx.x = x.x - mu; dx.y = x.y - mu; dx.z = x.z - mu; dx.w = x.w - mu;
    float vv = dx.x * dx.x + dx.y * dx.y + dx.z * dx.z + dx.w * dx.w;
    #pragma unroll
    for (int o = 32; o > 0; o >>= 1) vv += __shfl_xor(vv, o);
    const float rstd = rsqrtf(vv * (1.f / 256.f) + 1e-5f);

    const float4 gv  = *(const float4*)(g  + lane * 4);
    const float4 bev = *(const float4*)(be + lane * 4);
    float4 y;
    y.x = dx.x * rstd * gv.x + bev.x;
    y.y = dx.y * rstd * gv.y + bev.y;
    y.z = dx.z * rstd * gv.z + bev.z;
    y.w = dx.w * rstd * gv.w + bev.w;

    *(float4*)(xf + base) = y;
    if (xb) {
        ushort4 yb;
        yb.x = f2bf(y.x); yb.y = f2bf(y.y); yb.z = f2bf(y.z); yb.w = f2bf(y.w);
        *(ushort4*)(xb + base) = yb;
    }
}

// ---------------------------------------------------------------------------
extern "C" void kernel_launch(void* const* d_in, const int* in_sizes, int n_in,
                              void* d_out, int out_size, void* d_ws, size_t ws_size,
                              hipStream_t stream) {
    const float* src     = (const float*)d_in[0];
    const float* pos     = (const float*)d_in[1];
    const float* refp    = (const float*)d_in[2];
    const float* W_value = (const float*)d_in[4];
    const float* b_value = (const float*)d_in[5];
    const float* W_off   = (const float*)d_in[6];
    const float* b_off   = (const float*)d_in[7];
    const float* W_attn  = (const float*)d_in[8];
    const float* b_attn  = (const float*)d_in[9];
    const float* W_out   = (const float*)d_in[10];
    const float* b_out   = (const float*)d_in[11];
    const float* ln1g    = (const float*)d_in[12];
    const float* ln1b    = (const float*)d_in[13];
    const float* W1      = (const float*)d_in[14];
    const float* b1      = (const float*)d_in[15];
    const float* W2      = (const float*)d_in[16];
    const float* b2      = (const float*)d_in[17];
    const float* ln2g    = (const float*)d_in[18];
    const float* ln2b    = (const float*)d_in[19];
    float* out = (float*)d_out;
    char*  ws  = (char*)d_ws;

    // ---- workspace layout (byte offsets) ----
    const size_t SZ_BF = (size_t)NQ_ * 256 * 2;   // 22,282,240
    const size_t SZ_F  = (size_t)NQ_ * 256 * 4;   // 44,564,480
    ushort* s_bf    = (ushort*)(ws);                            // [0, 22.28M)
    ushort* q_bf    = (ushort*)(ws + SZ_BF);                    // [22.28M, 44.56M)
    ushort* val_bf  = (ushort*)(ws + 2 * SZ_BF);                // [44.56M, 66.85M)
    float*  comb    = (float*) (ws + 3 * SZ_BF);                // [66.85M, 133.69M)  NQ x 384 fp32
    ushort* samp_bf = (ushort*)(ws + 4 * SZ_BF + SZ_F);         // [133.69M, 155.98M)
    ushort* h_bf    = (ushort*)(ws);                            // overlays [0, 89.13M) — s/q/val/comb-head dead
    ushort* x_bf    = (ushort*)(ws + 3 * SZ_BF + SZ_F);         // overlays comb tail (dead after sampling)
    char*   wbase   = ws + 5 * SZ_BF + SZ_F;                    // 155.98M
    ushort* Wv_t    = (ushort*)(wbase);
    ushort* Woff_t  = (ushort*)(wbase + 131072);   // contiguous with Wattn_t -> one [384][256] Bt
    ushort* Wattn_t = (ushort*)(wbase + 262144);
    ushort* Wout_t  = (ushort*)(wbase + 327680);
    ushort* W1_t    = (ushort*)(wbase + 458752);
    ushort* W2_t    = (ushort*)(wbase + 983040);
    char*   fbase   = wbase + 1507328;
    float*  src2    = (float*)(fbase);                          // also ffn2
    float*  xf      = (float*)(fbase + SZ_F);

    // 0. bf16 inputs
    make_bf_inputs<<<dim3((NQ_ * 256 / 4) / 256), 256, 0, stream>>>(src, pos, s_bf, q_bf);
    // 0b. weight transposes (fp32 [K,N] -> bf16 [N,K])
    transpose_w<<<dim3(8, 8),  dim3(32, 8), 0, stream>>>(W_value, Wv_t,   256, 256);
    transpose_w<<<dim3(8, 8),  dim3(32, 8), 0, stream>>>(W_off,   Woff_t, 256, 256);
    transpose_w<<<dim3(4, 8),  dim3(32, 8), 0, stream>>>(W_attn,  Wattn_t,256, 128);
    transpose_w<<<dim3(8, 8),  dim3(32, 8), 0, stream>>>(W_out,   Wout_t, 256, 256);
    transpose_w<<<dim3(32, 8), dim3(32, 8), 0, stream>>>(W1,      W1_t,   256, 1024);
    transpose_w<<<dim3(8, 32), dim3(32, 8), 0, stream>>>(W2,      W2_t,   1024, 256);

    const int MT = NQ_ / BM;  // 340

    // 1. value = src @ Wv + bv  (bf16 out)
    mfma_gemm<<<dim3(2, MT), 256, 0, stream>>>(s_bf, Wv_t, b_value, nullptr, val_bf, 256, 256, 0);
    // 2. comb = q @ [Woff|Wattn]  (fp32, N=384, biases folded into msda_sample)
    mfma_gemm<<<dim3(3, MT), 256, 0, stream>>>(q_bf, Woff_t, nullptr, comb, nullptr, 384, 256, 0);
    // 3+4. fused softmax + sampling -> bf16
    msda_sample<<<dim3(NQ_ / QPB), 256, 0, stream>>>(val_bf, comb, b_off, b_attn, refp, samp_bf);
    // 5. src2 = sampled @ Wout + bout (fp32)
    mfma_gemm<<<dim3(2, MT), 256, 0, stream>>>(samp_bf, Wout_t, b_out, src2, nullptr, 256, 256, 0);
    // 6. x = LN(src + src2) -> fp32 + bf16
    add_ln<<<dim3(NQ_ / 4), 256, 0, stream>>>(src, src2, ln1g, ln1b, xf, x_bf);
    // 7. h = relu(x @ W1 + b1) -> bf16
    mfma_gemm<<<dim3(8, MT), 256, 0, stream>>>(x_bf, W1_t, b1, nullptr, h_bf, 1024, 256, 1);
    // 8. ffn2 = h @ W2 + b2 -> fp32 (overlays src2)
    mfma_gemm<<<dim3(2, MT), 256, 0, stream>>>(h_bf, W2_t, b2, src2, nullptr, 256, 1024, 0);
    // 9. out = LN(x + ffn2)
    add_ln<<<dim3(NQ_ / 4), 256, 0, stream>>>(xf, src2, ln2g, ln2b, out, nullptr);
}

// Round 3
// 527.037 us; speedup vs baseline: 1.0215x; 1.0215x over previous
//
#include <hip/hip_runtime.h>
#include <math.h>

#define LQ_ 5440
#define NB_ 8
#define NQ_ (NB_ * LQ_)   // 43520
#define D_  256
#define NH_ 8
#define HD_ 32

typedef __attribute__((ext_vector_type(8))) short short8;
typedef __attribute__((ext_vector_type(4))) float f32x4;
typedef __attribute__((ext_vector_type(2))) float f32x2;

__device__ __forceinline__ ushort f2bf(float f) {
    union { float f; unsigned u; } v; v.f = f;
    unsigned u = v.u;
    unsigned r = (u + 0x7FFFu + ((u >> 16) & 1u)) >> 16;
    return (ushort)r;
}

// async global->LDS, 16 B per lane. LDS dest = wave-uniform base + lane*16.
__device__ __forceinline__ void gload_lds16(const void* g, void* l) {
    __builtin_amdgcn_global_load_lds(
        (const __attribute__((address_space(1))) void*)g,
        (__attribute__((address_space(3))) void*)l, 16, 0, 0);
}

// ---------------------------------------------------------------------------
// Input prep: s_bf = bf16(src), q_bf = bf16(src+pos). 4 elems/thread.
// ---------------------------------------------------------------------------
__global__ void make_bf_inputs(const float* __restrict__ src, const float* __restrict__ pos,
                               ushort* __restrict__ s_bf, ushort* __restrict__ q_bf) {
    const int i = blockIdx.x * blockDim.x + threadIdx.x;
    const float4 s = ((const float4*)src)[i];
    const float4 p = ((const float4*)pos)[i];
    ushort4 a, b;
    a.x = f2bf(s.x); a.y = f2bf(s.y); a.z = f2bf(s.z); a.w = f2bf(s.w);
    b.x = f2bf(s.x + p.x); b.y = f2bf(s.y + p.y); b.z = f2bf(s.z + p.z); b.w = f2bf(s.w + p.w);
    ((ushort4*)s_bf)[i] = a;
    ((ushort4*)q_bf)[i] = b;
}

// ---------------------------------------------------------------------------
// Weight transpose + bf16 cast: W [K,N] fp32 -> Wt [N,K] bf16.
// ---------------------------------------------------------------------------
__global__ void transpose_w(const float* __restrict__ W, ushort* __restrict__ Wt, int K, int N) {
    __shared__ float tile[32][33];
    const int bx = blockIdx.x;   // n tile
    const int by = blockIdx.y;   // k tile
    const int tx = threadIdx.x;  // 0..31
    const int ty = threadIdx.y;  // 0..7
    for (int i = ty; i < 32; i += 8)
        tile[i][tx] = W[(size_t)(by * 32 + i) * N + bx * 32 + tx];
    __syncthreads();
    for (int i = ty; i < 32; i += 8)
        Wt[(size_t)(bx * 32 + i) * K + by * 32 + tx] = f2bf(tile[tx][i]);
}

// ---------------------------------------------------------------------------
// MFMA GEMM: C[M,N] = A[M,K](bf16) @ Bt[N,K](bf16)^T + bias, opt ReLU.
// 128x128 tile, BK=64, 4 waves, 4x4 16x16x32 tiles/wave.
// Double-buffered 2-phase loop: stage(k+1) issued BEFORE compute(k), ONE
// barrier per K-iter. global_load_lds width-16, linear LDS.
// ---------------------------------------------------------------------------
#define BM 128
#define BN 128
#define BK 64

__global__ __launch_bounds__(256)
void mfma_gemm(const ushort* __restrict__ A, const ushort* __restrict__ Bt,
               const float* __restrict__ bias, float* __restrict__ Cf,
               ushort* __restrict__ Cb, int N, int K, int relu) {
    __shared__ ushort lA[2][BM * BK];   // 2 x 16 KiB
    __shared__ ushort lB[2][BN * BK];   // 2 x 16 KiB
    const int t    = threadIdx.x;
    const int col0 = blockIdx.x * BN;
    const int row0 = blockIdx.y * BM;
    const int w    = t >> 6;
    const int lr   = t & 15;
    const int quad = (t >> 4) & 3;
    const int wm   = (w >> 1) * 64;
    const int wn   = (w & 1) * 64;

    f32x4 acc[4][4];
    #pragma unroll
    for (int i = 0; i < 4; ++i)
        #pragma unroll
        for (int j = 0; j < 4; ++j)
            acc[i][j] = (f32x4){0.f, 0.f, 0.f, 0.f};

    const int sr = t >> 3;
    const int sc = (t & 7) * 8;
    const size_t aoff = (size_t)(row0 + sr) * K + sc;
    const size_t boff = (size_t)(col0 + sr) * K + sc;
    const int wb = w * 1024;

    auto stage = [&](int buf, int k0) {
        char* la = (char*)lA[buf] + wb;
        char* lb = (char*)lB[buf] + wb;
        #pragma unroll
        for (int g = 0; g < 4; ++g) {
            gload_lds16(A  + aoff + k0 + (size_t)g * 32 * K, la + g * 4096);
            gload_lds16(Bt + boff + k0 + (size_t)g * 32 * K, lb + g * 4096);
        }
    };

    stage(0, 0);
    __syncthreads();               // drains vmcnt(0): buf0 ready
    int cur = 0;
    for (int k0 = 0; k0 < K; k0 += BK) {
        if (k0 + BK < K) stage(cur ^ 1, k0 + BK);   // prefetch next tile
        const ushort* pA = lA[cur];
        const ushort* pB = lB[cur];
        #pragma unroll
        for (int kk = 0; kk < 2; ++kk) {
            short8 af[4], bfr[4];
            #pragma unroll
            for (int i = 0; i < 4; ++i)
                af[i] = *(const short8*)(pA + (wm + i * 16 + lr) * BK + kk * 32 + quad * 8);
            #pragma unroll
            for (int j = 0; j < 4; ++j)
                bfr[j] = *(const short8*)(pB + (wn + j * 16 + lr) * BK + kk * 32 + quad * 8);
            #pragma unroll
            for (int i = 0; i < 4; ++i)
                #pragma unroll
                for (int j = 0; j < 4; ++j)
                    acc[i][j] = __builtin_amdgcn_mfma_f32_16x16x32_bf16(af[i], bfr[j], acc[i][j], 0, 0, 0);
        }
        __syncthreads();           // prefetch drained + all reads of cur done
        cur ^= 1;
    }

    #pragma unroll
    for (int j = 0; j < 4; ++j) {
        const int col = col0 + wn + j * 16 + lr;
        const float bb = bias ? bias[col] : 0.f;
        #pragma unroll
        for (int i = 0; i < 4; ++i) {
            const int rbase = row0 + wm + i * 16 + quad * 4;
            #pragma unroll
            for (int r = 0; r < 4; ++r) {
                float v = acc[i][j][r] + bb;
                if (relu) v = fmaxf(v, 0.f);
                if (Cf) Cf[(size_t)(rbase + r) * N + col] = v;
                else    Cb[(size_t)(rbase + r) * N + col] = f2bf(v);
            }
        }
    }
}

// ---------------------------------------------------------------------------
// Fused softmax + deformable bilinear sampling. (round-1 structure + pk_fma)
// Block = 256 threads, 2 queries/block (128 threads/query: max concurrency).
// Phase 1: thread u=(h,p): softmax + 4 corner BYTE offsets + 4 folded weights
//   stored PRE-DUPLICATED as {w,w} f32x2 (feeds v_pk_fma_f32 directly).
// Phase 2: thread u=(h,d2): saddr-form dword gathers; per corner:
//   1 v_add (addr) + 2 unpack + 1 v_pk_fma_f32  (was 2 scalar FMA).
//   Two acc pairs break the FMA dependency chain.
// Block swizzle: contiguous query ranges per XCD for gather L2 locality.
// ---------------------------------------------------------------------------
__global__ __launch_bounds__(256)
void msda_sample(const ushort* __restrict__ value, const float* __restrict__ comb,
                 const float* __restrict__ b_off, const float* __restrict__ b_attn,
                 const float* __restrict__ refp, ushort* __restrict__ out) {
    __shared__ int   s_addr[256][4];   // byte offsets into value (4 KiB)
    __shared__ f32x2 s_w[256][4];      // duplicated weights (8 KiB)

    const int t   = threadIdx.x;
    const int tq  = t >> 7;          // 0..1
    const int u   = t & 127;
    // bijective XCD swizzle: 21760 blocks = 8 XCDs x 2720 contiguous
    const int bid = blockIdx.x;
    const int swz = (bid & 7) * (NQ_ / 2 / 8) + (bid >> 3);
    const int nq  = swz * 2 + tq;
    const int n   = nq / LQ_;

    // ---------------- phase 1: (h,p) ----------------
    {
        const int h = u >> 4;
        const int p = u & 15;
        const int l = p >> 2;

        const int starts[4] = {0, 4096, 5120, 5376};
        const int Wl = 64 >> l;

        // softmax over 16 points (p = low 4 lane bits -> shfl_xor group)
        float a = comb[(size_t)nq * 384 + 256 + u] + b_attn[u];
        float m = a;
        #pragma unroll
        for (int o = 8; o > 0; o >>= 1) m = fmaxf(m, __shfl_xor(m, o));
        float e = __expf(a - m);
        float s = e;
        #pragma unroll
        for (int o = 8; o > 0; o >>= 1) s += __shfl_xor(s, o);
        const float wgt = e / s;

        const float rx = refp[(size_t)nq * 8 + l * 2 + 0];
        const float ry = refp[(size_t)nq * 8 + l * 2 + 1];
        const float ox = comb[(size_t)nq * 384 + u * 2 + 0] + b_off[u * 2 + 0];
        const float oy = comb[(size_t)nq * 384 + u * 2 + 1] + b_off[u * 2 + 1];

        const float fw = (float)Wl;
        const float x  = (rx + ox / fw) * fw - 0.5f;
        const float y  = (ry + oy / fw) * fw - 0.5f;
        const float x0f = floorf(x), y0f = floorf(y);
        const int   x0 = (int)x0f, y0 = (int)y0f;
        const float wx1 = x - x0f, wy1 = y - y0f;
        const float wx0 = 1.f - wx1, wy0 = 1.f - wy1;

        const float xm0 = (x0 >= 0 && x0 < Wl) ? 1.f : 0.f;
        const float xm1 = (x0 + 1 >= 0 && x0 + 1 < Wl) ? 1.f : 0.f;
        const float ym0 = (y0 >= 0 && y0 < Wl) ? 1.f : 0.f;
        const float ym1 = (y0 + 1 >= 0 && y0 + 1 < Wl) ? 1.f : 0.f;

        const int x0c = min(max(x0, 0), Wl - 1);
        const int x1c = min(max(x0 + 1, 0), Wl - 1);
        const int y0c = min(max(y0, 0), Wl - 1);
        const int y1c = min(max(y0 + 1, 0), Wl - 1);

        // BYTE offsets: value row = 256 bf16 = 512 B; head offset = h*64 B
        const int base = (n * LQ_ + starts[l]) * 512 + h * 64;
        s_addr[t][0] = base + (y0c * Wl + x0c) * 512;
        s_addr[t][1] = base + (y0c * Wl + x1c) * 512;
        s_addr[t][2] = base + (y1c * Wl + x0c) * 512;
        s_addr[t][3] = base + (y1c * Wl + x1c) * 512;
        const float w0 = wgt * wy0 * wx0 * ym0 * xm0;
        const float w1 = wgt * wy0 * wx1 * ym0 * xm1;
        const float w2 = wgt * wy1 * wx0 * ym1 * xm0;
        const float w3 = wgt * wy1 * wx1 * ym1 * xm1;
        s_w[t][0] = (f32x2){w0, w0};
        s_w[t][1] = (f32x2){w1, w1};
        s_w[t][2] = (f32x2){w2, w2};
        s_w[t][3] = (f32x2){w3, w3};
    }
    __syncthreads();

    // ---------------- phase 2: (h,d2) ----------------
    {
        const int h   = u >> 4;
        const int d2  = u & 15;                  // uint index: elems 2*d2, 2*d2+1
        const int sb  = tq * 128 + h * 16;
        const uint dby = (uint)(d2 * 4);         // byte offset of this uint in row
        const char* vbase = (const char*)value;

        f32x2 accA = (f32x2){0.f, 0.f};
        f32x2 accB = (f32x2){0.f, 0.f};
        #pragma unroll 8
        for (int p = 0; p < 16; ++p) {
            const int*   ap = s_addr[sb + p];
            const f32x2* wp = s_w[sb + p];
            #pragma unroll
            for (int c = 0; c < 4; ++c) {
                const uint v = *(const uint*)(vbase + ((uint)ap[c] + dby));
                union { uint u; float f; } lo, hi;
                lo.u = v << 16;            // bf16 lane 0 -> f32
                hi.u = v & 0xffff0000u;    // bf16 lane 1 -> f32
                f32x2 vals = (f32x2){lo.f, hi.f};
                if (c & 1)
                    asm("v_pk_fma_f32 %0, %1, %2, %0" : "+v"(accB) : "v"(vals), "v"(wp[c]));
                else
                    asm("v_pk_fma_f32 %0, %1, %2, %0" : "+v"(accA) : "v"(vals), "v"(wp[c]));
            }
        }
        const float a0 = accA.x + accB.x;
        const float a1 = accA.y + accB.y;
        const uint packed = (uint)f2bf(a0) | ((uint)f2bf(a1) << 16);
        ((uint*)out)[(size_t)nq * 128 + u] = packed;
    }
}

// ---------------------------------------------------------------------------
// x = LayerNorm(a + b); wave-per-row, float4 per lane, shuffle-only reduce.
// grid = NQ/4, block = 256 (4 waves = 4 rows).
// ---------------------------------------------------------------------------
__global__ __launch_bounds__(256)
void add_ln(const float* __restrict__ a, const float* __restrict__ b,
            const float* __restrict__ g, const float* __restrict__ be,
            float* __restrict__ xf, ushort* __restrict__ xb) {
    const int row  = blockIdx.x * 4 + (threadIdx.x >> 6);
    const int lane = threadIdx.x & 63;
    const size_t base = (size_t)row * 256 + lane * 4;

    const float4 av = *(const float4*)(a + base);
    const float4 bv = *(const float4*)(b + base);
    float4 x;
    x.x = av.x + bv.x; x.y = av.y + bv.y; x.z = av.z + bv.z; x.w = av.w + bv.w;

    float s = x.x + x.y + x.z + x.w;
    #pragma unroll
    for (int o = 32; o > 0; o >>= 1) s += __shfl_xor(s, o);
    const float mu = s * (1.f / 256.f);

    float4 dx;
    dx.x = x.x - mu; dx.y = x.y - mu; dx.z = x.z - mu; dx.w = x.w - mu;
    float vv = dx.x * dx.x + dx.y * dx.y + dx.z * dx.z + dx.w * dx.w;
    #pragma unroll
    for (int o = 32; o > 0; o >>= 1) vv += __shfl_xor(vv, o);
    const float rstd = rsqrtf(vv * (1.f / 256.f) + 1e-5f);

    const float4 gv  = *(const float4*)(g  + lane * 4);
    const float4 bev = *(const float4*)(be + lane * 4);
    float4 y;
    y.x = dx.x * rstd * gv.x + bev.x;
    y.y = dx.y * rstd * gv.y + bev.y;
    y.z = dx.z * rstd * gv.z + bev.z;
    y.w = dx.w * rstd * gv.w + bev.w;

    *(float4*)(xf + base) = y;
    if (xb) {
        ushort4 yb;
        yb.x = f2bf(y.x); yb.y = f2bf(y.y); yb.z = f2bf(y.z); yb.w = f2bf(y.w);
        *(ushort4*)(xb + base) = yb;
    }
}

// ---------------------------------------------------------------------------
extern "C" void kernel_launch(void* const* d_in, const int* in_sizes, int n_in,
                              void* d_out, int out_size, void* d_ws, size_t ws_size,
                              hipStream_t stream) {
    const float* src     = (const float*)d_in[0];
    const float* pos     = (const float*)d_in[1];
    const float* refp    = (const float*)d_in[2];
    const float* W_value = (const float*)d_in[4];
    const float* b_value = (const float*)d_in[5];
    const float* W_off   = (const float*)d_in[6];
    const float* b_off   = (const float*)d_in[7];
    const float* W_attn  = (const float*)d_in[8];
    const float* b_attn  = (const float*)d_in[9];
    const float* W_out   = (const float*)d_in[10];
    const float* b_out   = (const float*)d_in[11];
    const float* ln1g    = (const float*)d_in[12];
    const float* ln1b    = (const float*)d_in[13];
    const float* W1      = (const float*)d_in[14];
    const float* b1      = (const float*)d_in[15];
    const float* W2      = (const float*)d_in[16];
    const float* b2      = (const float*)d_in[17];
    const float* ln2g    = (const float*)d_in[18];
    const float* ln2b    = (const float*)d_in[19];
    float* out = (float*)d_out;
    char*  ws  = (char*)d_ws;

    // ---- workspace layout (byte offsets) ----
    const size_t SZ_BF = (size_t)NQ_ * 256 * 2;   // 22,282,240
    const size_t SZ_F  = (size_t)NQ_ * 256 * 4;   // 44,564,480
    ushort* s_bf    = (ushort*)(ws);                            // [0, 22.28M)
    ushort* q_bf    = (ushort*)(ws + SZ_BF);                    // [22.28M, 44.56M)
    ushort* val_bf  = (ushort*)(ws + 2 * SZ_BF);                // [44.56M, 66.85M)
    float*  comb    = (float*) (ws + 3 * SZ_BF);                // [66.85M, 133.69M)  NQ x 384 fp32
    ushort* samp_bf = (ushort*)(ws + 4 * SZ_BF + SZ_F);         // [133.69M, 155.98M)
    ushort* h_bf    = (ushort*)(ws);                            // overlays [0, 89.13M) — s/q/val/comb-head dead
    ushort* x_bf    = (ushort*)(ws + 3 * SZ_BF + SZ_F);         // overlays comb tail (dead after sampling)
    char*   wbase   = ws + 5 * SZ_BF + SZ_F;                    // 155.98M
    ushort* Wv_t    = (ushort*)(wbase);
    ushort* Woff_t  = (ushort*)(wbase + 131072);   // contiguous with Wattn_t -> one [384][256] Bt
    ushort* Wattn_t = (ushort*)(wbase + 262144);
    ushort* Wout_t  = (ushort*)(wbase + 327680);
    ushort* W1_t    = (ushort*)(wbase + 458752);
    ushort* W2_t    = (ushort*)(wbase + 983040);
    char*   fbase   = wbase + 1507328;
    float*  src2    = (float*)(fbase);                          // also ffn2
    float*  xf      = (float*)(fbase + SZ_F);

    // 0. bf16 inputs
    make_bf_inputs<<<dim3((NQ_ * 256 / 4) / 256), 256, 0, stream>>>(src, pos, s_bf, q_bf);
    // 0b. weight transposes (fp32 [K,N] -> bf16 [N,K])
    transpose_w<<<dim3(8, 8),  dim3(32, 8), 0, stream>>>(W_value, Wv_t,   256, 256);
    transpose_w<<<dim3(8, 8),  dim3(32, 8), 0, stream>>>(W_off,   Woff_t, 256, 256);
    transpose_w<<<dim3(4, 8),  dim3(32, 8), 0, stream>>>(W_attn,  Wattn_t,256, 128);
    transpose_w<<<dim3(8, 8),  dim3(32, 8), 0, stream>>>(W_out,   Wout_t, 256, 256);
    transpose_w<<<dim3(32, 8), dim3(32, 8), 0, stream>>>(W1,      W1_t,   256, 1024);
    transpose_w<<<dim3(8, 32), dim3(32, 8), 0, stream>>>(W2,      W2_t,   1024, 256);

    const int MT = NQ_ / BM;  // 340

    // 1. value = src @ Wv + bv  (bf16 out)
    mfma_gemm<<<dim3(2, MT), 256, 0, stream>>>(s_bf, Wv_t, b_value, nullptr, val_bf, 256, 256, 0);
    // 2. comb = q @ [Woff|Wattn]  (fp32, N=384, biases folded into msda_sample)
    mfma_gemm<<<dim3(3, MT), 256, 0, stream>>>(q_bf, Woff_t, nullptr, comb, nullptr, 384, 256, 0);
    // 3+4. fused softmax + sampling -> bf16
    msda_sample<<<dim3(NQ_ / 2), 256, 0, stream>>>(val_bf, comb, b_off, b_attn, refp, samp_bf);
    // 5. src2 = sampled @ Wout + bout (fp32)
    mfma_gemm<<<dim3(2, MT), 256, 0, stream>>>(samp_bf, Wout_t, b_out, src2, nullptr, 256, 256, 0);
    // 6. x = LN(src + src2) -> fp32 + bf16
    add_ln<<<dim3(NQ_ / 4), 256, 0, stream>>>(src, src2, ln1g, ln1b, xf, x_bf);
    // 7. h = relu(x @ W1 + b1) -> bf16
    mfma_gemm<<<dim3(8, MT), 256, 0, stream>>>(x_bf, W1_t, b1, nullptr, h_bf, 1024, 256, 1);
    // 8. ffn2 = h @ W2 + b2 -> fp32 (overlays src2)
    mfma_gemm<<<dim3(2, MT), 256, 0, stream>>>(h_bf, W2_t, b2, src2, nullptr, 256, 1024, 0);
    // 9. out = LN(x + ffn2)
    add_ln<<<dim3(NQ_ / 4), 256, 0, stream>>>(xf, src2, ln2g, ln2b, out, nullptr);
}

// Round 4
// 498.908 us; speedup vs baseline: 1.0791x; 1.0564x over previous
//
#include <hip/hip_runtime.h>
#include <math.h>

#define LQ_ 5440
#define NB_ 8
#define NQ_ (NB_ * LQ_)   // 43520
#define D_  256
#define NH_ 8
#define HD_ 32

typedef __attribute__((ext_vector_type(8))) short short8;
typedef __attribute__((ext_vector_type(4))) float f32x4;

__device__ __forceinline__ ushort f2bf(float f) {
    union { float f; unsigned u; } v; v.f = f;
    unsigned u = v.u;
    unsigned r = (u + 0x7FFFu + ((u >> 16) & 1u)) >> 16;
    return (ushort)r;
}

// async global->LDS, 16 B per lane. LDS dest = wave-uniform base + lane*16.
__device__ __forceinline__ void gload_lds16(const void* g, void* l) {
    __builtin_amdgcn_global_load_lds(
        (const __attribute__((address_space(1))) void*)g,
        (__attribute__((address_space(3))) void*)l, 16, 0, 0);
}

// raw workgroup barrier, fenced so no memory op is scheduled across it.
__device__ __forceinline__ void wg_barrier() {
    __builtin_amdgcn_sched_barrier(0);
    __builtin_amdgcn_s_barrier();
    __builtin_amdgcn_sched_barrier(0);
}

// ---------------------------------------------------------------------------
// Input prep: s_bf = bf16(src), q_bf = bf16(src+pos). 4 elems/thread.
// ---------------------------------------------------------------------------
__global__ void make_bf_inputs(const float* __restrict__ src, const float* __restrict__ pos,
                               ushort* __restrict__ s_bf, ushort* __restrict__ q_bf) {
    const int i = blockIdx.x * blockDim.x + threadIdx.x;
    const float4 s = ((const float4*)src)[i];
    const float4 p = ((const float4*)pos)[i];
    ushort4 a, b;
    a.x = f2bf(s.x); a.y = f2bf(s.y); a.z = f2bf(s.z); a.w = f2bf(s.w);
    b.x = f2bf(s.x + p.x); b.y = f2bf(s.y + p.y); b.z = f2bf(s.z + p.z); b.w = f2bf(s.w + p.w);
    ((ushort4*)s_bf)[i] = a;
    ((ushort4*)q_bf)[i] = b;
}

// ---------------------------------------------------------------------------
// Weight transpose + bf16 cast: W [K,N] fp32 -> Wt [N,K] bf16.
// ---------------------------------------------------------------------------
__global__ void transpose_w(const float* __restrict__ W, ushort* __restrict__ Wt, int K, int N) {
    __shared__ float tile[32][33];
    const int bx = blockIdx.x;   // n tile
    const int by = blockIdx.y;   // k tile
    const int tx = threadIdx.x;  // 0..31
    const int ty = threadIdx.y;  // 0..7
    for (int i = ty; i < 32; i += 8)
        tile[i][tx] = W[(size_t)(by * 32 + i) * N + bx * 32 + tx];
    __syncthreads();
    for (int i = ty; i < 32; i += 8)
        Wt[(size_t)(bx * 32 + i) * K + by * 32 + tx] = f2bf(tile[tx][i]);
}

// ---------------------------------------------------------------------------
// MFMA GEMM: C[M,N] = A[M,K](bf16) @ Bt[N,K](bf16)^T + bias, opt ReLU.
// 128x128 tile, BK=64, 4 waves, 4x4 16x16x32 tiles/wave.
// Double-buffered with COUNTED vmcnt (T4): stage(k+1) issued before
// compute(k); per-iter wait is s_waitcnt vmcnt(8) — only the PREVIOUS
// tile's 8 global_load_lds must land; the fresh 8 stay in flight across
// the barrier. (__syncthreads would drain vmcnt(0) and kill the prefetch.)
// ---------------------------------------------------------------------------
#define BM 128
#define BN 128
#define BK 64

__global__ __launch_bounds__(256)
void mfma_gemm(const ushort* __restrict__ A, const ushort* __restrict__ Bt,
               const float* __restrict__ bias, float* __restrict__ Cf,
               ushort* __restrict__ Cb, int N, int K, int relu) {
    __shared__ ushort lA[2][BM * BK];   // 2 x 16 KiB
    __shared__ ushort lB[2][BN * BK];   // 2 x 16 KiB
    const int t    = threadIdx.x;
    const int col0 = blockIdx.x * BN;
    const int row0 = blockIdx.y * BM;
    const int w    = t >> 6;
    const int lr   = t & 15;
    const int quad = (t >> 4) & 3;
    const int wm   = (w >> 1) * 64;
    const int wn   = (w & 1) * 64;

    f32x4 acc[4][4];
    #pragma unroll
    for (int i = 0; i < 4; ++i)
        #pragma unroll
        for (int j = 0; j < 4; ++j)
            acc[i][j] = (f32x4){0.f, 0.f, 0.f, 0.f};

    const int sr = t >> 3;
    const int sc = (t & 7) * 8;
    const size_t aoff = (size_t)(row0 + sr) * K + sc;
    const size_t boff = (size_t)(col0 + sr) * K + sc;
    const int wb = w * 1024;

    auto stage = [&](int buf, int k0) {
        char* la = (char*)lA[buf] + wb;
        char* lb = (char*)lB[buf] + wb;
        #pragma unroll
        for (int g = 0; g < 4; ++g) {
            gload_lds16(A  + aoff + k0 + (size_t)g * 32 * K, la + g * 4096);
            gload_lds16(Bt + boff + k0 + (size_t)g * 32 * K, lb + g * 4096);
        }
    };

    stage(0, 0);                       // 8 loads in flight
    int cur = 0;
    for (int k0 = 0; k0 < K; k0 += BK) {
        if (k0 + BK < K) {
            stage(cur ^ 1, k0 + BK);   // +8 loads (16 in flight)
            asm volatile("s_waitcnt vmcnt(8)" ::: "memory");  // prev tile landed
        } else {
            asm volatile("s_waitcnt vmcnt(0)" ::: "memory");  // final tile
        }
        wg_barrier();                  // all waves' cur-tile stages visible
        const ushort* pA = lA[cur];
        const ushort* pB = lB[cur];
        #pragma unroll
        for (int kk = 0; kk < 2; ++kk) {
            short8 af[4], bfr[4];
            #pragma unroll
            for (int i = 0; i < 4; ++i)
                af[i] = *(const short8*)(pA + (wm + i * 16 + lr) * BK + kk * 32 + quad * 8);
            #pragma unroll
            for (int j = 0; j < 4; ++j)
                bfr[j] = *(const short8*)(pB + (wn + j * 16 + lr) * BK + kk * 32 + quad * 8);
            #pragma unroll
            for (int i = 0; i < 4; ++i)
                #pragma unroll
                for (int j = 0; j < 4; ++j)
                    acc[i][j] = __builtin_amdgcn_mfma_f32_16x16x32_bf16(af[i], bfr[j], acc[i][j], 0, 0, 0);
        }
        wg_barrier();                  // cur fully read before it is re-staged
        cur ^= 1;
    }

    #pragma unroll
    for (int j = 0; j < 4; ++j) {
        const int col = col0 + wn + j * 16 + lr;
        const float bb = bias ? bias[col] : 0.f;
        #pragma unroll
        for (int i = 0; i < 4; ++i) {
            const int rbase = row0 + wm + i * 16 + quad * 4;
            #pragma unroll
            for (int r = 0; r < 4; ++r) {
                float v = acc[i][j][r] + bb;
                if (relu) v = fmaxf(v, 0.f);
                if (Cf) Cf[(size_t)(rbase + r) * N + col] = v;
                else    Cb[(size_t)(rbase + r) * N + col] = f2bf(v);
            }
        }
    }
}

// ---------------------------------------------------------------------------
// Fused softmax + deformable bilinear sampling.  (round-1 proven structure:
// 2 queries/block, 128 threads/query, scalar FMA; + XCD swizzle from r3.)
// Phase 1: thread u=(h,p): softmax + 4 corner BYTE offsets + 4 folded wts.
// Phase 2: thread u=(h,d2): saddr-form dword gathers, 2 scalar FMA/corner.
// ---------------------------------------------------------------------------
__global__ __launch_bounds__(256)
void msda_sample(const ushort* __restrict__ value, const float* __restrict__ comb,
                 const float* __restrict__ b_off, const float* __restrict__ b_attn,
                 const float* __restrict__ refp, ushort* __restrict__ out) {
    __shared__ int   s_addr[256][4];   // byte offsets into value (4 KiB)
    __shared__ float s_w[256][4];      // folded weights (4 KiB)

    const int t   = threadIdx.x;
    const int tq  = t >> 7;          // 0..1
    const int u   = t & 127;
    // bijective XCD swizzle: 21760 blocks = 8 XCDs x 2720 contiguous
    const int bid = blockIdx.x;
    const int swz = (bid & 7) * (NQ_ / 2 / 8) + (bid >> 3);
    const int nq  = swz * 2 + tq;
    const int n   = nq / LQ_;

    // ---------------- phase 1: (h,p) ----------------
    {
        const int h = u >> 4;
        const int p = u & 15;
        const int l = p >> 2;

        const int starts[4] = {0, 4096, 5120, 5376};
        const int Wl = 64 >> l;

        // softmax over 16 points (p = low 4 lane bits -> shfl_xor group)
        float a = comb[(size_t)nq * 384 + 256 + u] + b_attn[u];
        float m = a;
        #pragma unroll
        for (int o = 8; o > 0; o >>= 1) m = fmaxf(m, __shfl_xor(m, o));
        float e = __expf(a - m);
        float s = e;
        #pragma unroll
        for (int o = 8; o > 0; o >>= 1) s += __shfl_xor(s, o);
        const float wgt = e / s;

        const float rx = refp[(size_t)nq * 8 + l * 2 + 0];
        const float ry = refp[(size_t)nq * 8 + l * 2 + 1];
        const float ox = comb[(size_t)nq * 384 + u * 2 + 0] + b_off[u * 2 + 0];
        const float oy = comb[(size_t)nq * 384 + u * 2 + 1] + b_off[u * 2 + 1];

        const float fw = (float)Wl;
        const float x  = (rx + ox / fw) * fw - 0.5f;
        const float y  = (ry + oy / fw) * fw - 0.5f;
        const float x0f = floorf(x), y0f = floorf(y);
        const int   x0 = (int)x0f, y0 = (int)y0f;
        const float wx1 = x - x0f, wy1 = y - y0f;
        const float wx0 = 1.f - wx1, wy0 = 1.f - wy1;

        const float xm0 = (x0 >= 0 && x0 < Wl) ? 1.f : 0.f;
        const float xm1 = (x0 + 1 >= 0 && x0 + 1 < Wl) ? 1.f : 0.f;
        const float ym0 = (y0 >= 0 && y0 < Wl) ? 1.f : 0.f;
        const float ym1 = (y0 + 1 >= 0 && y0 + 1 < Wl) ? 1.f : 0.f;

        const int x0c = min(max(x0, 0), Wl - 1);
        const int x1c = min(max(x0 + 1, 0), Wl - 1);
        const int y0c = min(max(y0, 0), Wl - 1);
        const int y1c = min(max(y0 + 1, 0), Wl - 1);

        // BYTE offsets: value row = 256 bf16 = 512 B; head offset = h*64 B
        const int base = (n * LQ_ + starts[l]) * 512 + h * 64;
        s_addr[t][0] = base + (y0c * Wl + x0c) * 512;
        s_addr[t][1] = base + (y0c * Wl + x1c) * 512;
        s_addr[t][2] = base + (y1c * Wl + x0c) * 512;
        s_addr[t][3] = base + (y1c * Wl + x1c) * 512;
        s_w[t][0] = wgt * wy0 * wx0 * ym0 * xm0;
        s_w[t][1] = wgt * wy0 * wx1 * ym0 * xm1;
        s_w[t][2] = wgt * wy1 * wx0 * ym1 * xm0;
        s_w[t][3] = wgt * wy1 * wx1 * ym1 * xm1;
    }
    __syncthreads();

    // ---------------- phase 2: (h,d2) ----------------
    {
        const int h   = u >> 4;
        const int d2  = u & 15;                  // uint index: elems 2*d2, 2*d2+1
        const int sb  = tq * 128 + h * 16;
        const uint dby = (uint)(d2 * 4);         // byte offset of this uint in row
        const char* vbase = (const char*)value;

        float acc0 = 0.f, acc1 = 0.f;
        #pragma unroll 8
        for (int p = 0; p < 16; ++p) {
            const int*   ap = s_addr[sb + p];
            const float* wp = s_w[sb + p];
            #pragma unroll
            for (int c = 0; c < 4; ++c) {
                const uint v = *(const uint*)(vbase + ((uint)ap[c] + dby));
                const float w = wp[c];
                union { uint u; float f; } lo, hi;
                lo.u = v << 16;            // bf16 lane 0 -> f32
                hi.u = v & 0xffff0000u;    // bf16 lane 1 -> f32
                acc0 = fmaf(lo.f, w, acc0);
                acc1 = fmaf(hi.f, w, acc1);
            }
        }
        const uint packed = (uint)f2bf(acc0) | ((uint)f2bf(acc1) << 16);
        ((uint*)out)[(size_t)nq * 128 + u] = packed;
    }
}

// ---------------------------------------------------------------------------
// x = LayerNorm(a + b); wave-per-row, float4 per lane, shuffle-only reduce.
// grid = NQ/4, block = 256 (4 waves = 4 rows).
// ---------------------------------------------------------------------------
__global__ __launch_bounds__(256)
void add_ln(const float* __restrict__ a, const float* __restrict__ b,
            const float* __restrict__ g, const float* __restrict__ be,
            float* __restrict__ xf, ushort* __restrict__ xb) {
    const int row  = blockIdx.x * 4 + (threadIdx.x >> 6);
    const int lane = threadIdx.x & 63;
    const size_t base = (size_t)row * 256 + lane * 4;

    const float4 av = *(const float4*)(a + base);
    const float4 bv = *(const float4*)(b + base);
    float4 x;
    x.x = av.x + bv.x; x.y = av.y + bv.y; x.z = av.z + bv.z; x.w = av.w + bv.w;

    float s = x.x + x.y + x.z + x.w;
    #pragma unroll
    for (int o = 32; o > 0; o >>= 1) s += __shfl_xor(s, o);
    const float mu = s * (1.f / 256.f);

    float4 dx;
    dx.x = x.x - mu; dx.y = x.y - mu; dx.z = x.z - mu; dx.w = x.w - mu;
    float vv = dx.x * dx.x + dx.y * dx.y + dx.z * dx.z + dx.w * dx.w;
    #pragma unroll
    for (int o = 32; o > 0; o >>= 1) vv += __shfl_xor(vv, o);
    const float rstd = rsqrtf(vv * (1.f / 256.f) + 1e-5f);

    const float4 gv  = *(const float4*)(g  + lane * 4);
    const float4 bev = *(const float4*)(be + lane * 4);
    float4 y;
    y.x = dx.x * rstd * gv.x + bev.x;
    y.y = dx.y * rstd * gv.y + bev.y;
    y.z = dx.z * rstd * gv.z + bev.z;
    y.w = dx.w * rstd * gv.w + bev.w;

    *(float4*)(xf + base) = y;
    if (xb) {
        ushort4 yb;
        yb.x = f2bf(y.x); yb.y = f2bf(y.y); yb.z = f2bf(y.z); yb.w = f2bf(y.w);
        *(ushort4*)(xb + base) = yb;
    }
}

// ---------------------------------------------------------------------------
extern "C" void kernel_launch(void* const* d_in, const int* in_sizes, int n_in,
                              void* d_out, int out_size, void* d_ws, size_t ws_size,
                              hipStream_t stream) {
    const float* src     = (const float*)d_in[0];
    const float* pos     = (const float*)d_in[1];
    const float* refp    = (const float*)d_in[2];
    const float* W_value = (const float*)d_in[4];
    const float* b_value = (const float*)d_in[5];
    const float* W_off   = (const float*)d_in[6];
    const float* b_off   = (const float*)d_in[7];
    const float* W_attn  = (const float*)d_in[8];
    const float* b_attn  = (const float*)d_in[9];
    const float* W_out   = (const float*)d_in[10];
    const float* b_out   = (const float*)d_in[11];
    const float* ln1g    = (const float*)d_in[12];
    const float* ln1b    = (const float*)d_in[13];
    const float* W1      = (const float*)d_in[14];
    const float* b1      = (const float*)d_in[15];
    const float* W2      = (const float*)d_in[16];
    const float* b2      = (const float*)d_in[17];
    const float* ln2g    = (const float*)d_in[18];
    const float* ln2b    = (const float*)d_in[19];
    float* out = (float*)d_out;
    char*  ws  = (char*)d_ws;

    // ---- workspace layout (byte offsets) ----
    const size_t SZ_BF = (size_t)NQ_ * 256 * 2;   // 22,282,240
    const size_t SZ_F  = (size_t)NQ_ * 256 * 4;   // 44,564,480
    ushort* s_bf    = (ushort*)(ws);                            // [0, 22.28M)
    ushort* q_bf    = (ushort*)(ws + SZ_BF);                    // [22.28M, 44.56M)
    ushort* val_bf  = (ushort*)(ws + 2 * SZ_BF);                // [44.56M, 66.85M)
    float*  comb    = (float*) (ws + 3 * SZ_BF);                // [66.85M, 133.69M)  NQ x 384 fp32
    ushort* samp_bf = (ushort*)(ws + 4 * SZ_BF + SZ_F);         // [133.69M, 155.98M)
    ushort* h_bf    = (ushort*)(ws);                            // overlays [0, 89.13M) — s/q/val/comb-head dead
    ushort* x_bf    = (ushort*)(ws + 3 * SZ_BF + SZ_F);         // overlays comb tail (dead after sampling)
    char*   wbase   = ws + 5 * SZ_BF + SZ_F;                    // 155.98M
    ushort* Wv_t    = (ushort*)(wbase);
    ushort* Woff_t  = (ushort*)(wbase + 131072);   // contiguous with Wattn_t -> one [384][256] Bt
    ushort* Wattn_t = (ushort*)(wbase + 262144);
    ushort* Wout_t  = (ushort*)(wbase + 327680);
    ushort* W1_t    = (ushort*)(wbase + 458752);
    ushort* W2_t    = (ushort*)(wbase + 983040);
    char*   fbase   = wbase + 1507328;
    float*  src2    = (float*)(fbase);                          // also ffn2
    float*  xf      = (float*)(fbase + SZ_F);

    // 0. bf16 inputs
    make_bf_inputs<<<dim3((NQ_ * 256 / 4) / 256), 256, 0, stream>>>(src, pos, s_bf, q_bf);
    // 0b. weight transposes (fp32 [K,N] -> bf16 [N,K])
    transpose_w<<<dim3(8, 8),  dim3(32, 8), 0, stream>>>(W_value, Wv_t,   256, 256);
    transpose_w<<<dim3(8, 8),  dim3(32, 8), 0, stream>>>(W_off,   Woff_t, 256, 256);
    transpose_w<<<dim3(4, 8),  dim3(32, 8), 0, stream>>>(W_attn,  Wattn_t,256, 128);
    transpose_w<<<dim3(8, 8),  dim3(32, 8), 0, stream>>>(W_out,   Wout_t, 256, 256);
    transpose_w<<<dim3(32, 8), dim3(32, 8), 0, stream>>>(W1,      W1_t,   256, 1024);
    transpose_w<<<dim3(8, 32), dim3(32, 8), 0, stream>>>(W2,      W2_t,   1024, 256);

    const int MT = NQ_ / BM;  // 340

    // 1. value = src @ Wv + bv  (bf16 out)
    mfma_gemm<<<dim3(2, MT), 256, 0, stream>>>(s_bf, Wv_t, b_value, nullptr, val_bf, 256, 256, 0);
    // 2. comb = q @ [Woff|Wattn]  (fp32, N=384, biases folded into msda_sample)
    mfma_gemm<<<dim3(3, MT), 256, 0, stream>>>(q_bf, Woff_t, nullptr, comb, nullptr, 384, 256, 0);
    // 3+4. fused softmax + sampling -> bf16
    msda_sample<<<dim3(NQ_ / 2), 256, 0, stream>>>(val_bf, comb, b_off, b_attn, refp, samp_bf);
    // 5. src2 = sampled @ Wout + bout (fp32)
    mfma_gemm<<<dim3(2, MT), 256, 0, stream>>>(samp_bf, Wout_t, b_out, src2, nullptr, 256, 256, 0);
    // 6. x = LN(src + src2) -> fp32 + bf16
    add_ln<<<dim3(NQ_ / 4), 256, 0, stream>>>(src, src2, ln1g, ln1b, xf, x_bf);
    // 7. h = relu(x @ W1 + b1) -> bf16
    mfma_gemm<<<dim3(8, MT), 256, 0, stream>>>(x_bf, W1_t, b1, nullptr, h_bf, 1024, 256, 1);
    // 8. ffn2 = h @ W2 + b2 -> fp32 (overlays src2)
    mfma_gemm<<<dim3(2, MT), 256, 0, stream>>>(h_bf, W2_t, b2, src2, nullptr, 256, 1024, 0);
    // 9. out = LN(x + ffn2)
    add_ln<<<dim3(NQ_ / 4), 256, 0, stream>>>(xf, src2, ln2g, ln2b, out, nullptr);
}

// Round 5
// 487.776 us; speedup vs baseline: 1.1037x; 1.0228x over previous
//
#include <hip/hip_runtime.h>
#include <math.h>

#define LQ_ 5440
#define NB_ 8
#define NQ_ (NB_ * LQ_)   // 43520
#define D_  256
#define NH_ 8
#define HD_ 32

typedef __attribute__((ext_vector_type(8))) short short8;
typedef __attribute__((ext_vector_type(4))) float f32x4;

__device__ __forceinline__ ushort f2bf(float f) {
    union { float f; unsigned u; } v; v.f = f;
    unsigned u = v.u;
    unsigned r = (u + 0x7FFFu + ((u >> 16) & 1u)) >> 16;
    return (ushort)r;
}

// async global->LDS, 16 B per lane. LDS dest = wave-uniform base + lane*16.
__device__ __forceinline__ void gload_lds16(const void* g, void* l) {
    __builtin_amdgcn_global_load_lds(
        (const __attribute__((address_space(1))) void*)g,
        (__attribute__((address_space(3))) void*)l, 16, 0, 0);
}

// raw workgroup barrier, fenced so no memory op is scheduled across it.
__device__ __forceinline__ void wg_barrier() {
    __builtin_amdgcn_sched_barrier(0);
    __builtin_amdgcn_s_barrier();
    __builtin_amdgcn_sched_barrier(0);
}

// ---------------------------------------------------------------------------
// Fused prep: ONE launch for bf16 input casts + all 6 weight transposes.
// Blocks [0,736): transposes; blocks [736, 736+10880): make_bf.
// ---------------------------------------------------------------------------
#define TPREP_ 736

__global__ __launch_bounds__(256)
void prep(const float* __restrict__ src, const float* __restrict__ pos,
          ushort* __restrict__ s_bf, ushort* __restrict__ q_bf,
          const float* __restrict__ Wv, const float* __restrict__ Woff,
          const float* __restrict__ Wattn, const float* __restrict__ Wout,
          const float* __restrict__ W1, const float* __restrict__ W2,
          ushort* __restrict__ Wv_t, ushort* __restrict__ Woff_t,
          ushort* __restrict__ Wattn_t, ushort* __restrict__ Wout_t,
          ushort* __restrict__ W1_t, ushort* __restrict__ W2_t) {
    __shared__ float tile[32][33];
    const int bid = blockIdx.x;
    const int tid = threadIdx.x;

    if (bid >= TPREP_) {
        // ---- bf16 inputs: s_bf = bf16(src), q_bf = bf16(src+pos) ----
        const int i = (bid - TPREP_) * 256 + tid;
        const float4 s = ((const float4*)src)[i];
        const float4 p = ((const float4*)pos)[i];
        ushort4 a, b;
        a.x = f2bf(s.x); a.y = f2bf(s.y); a.z = f2bf(s.z); a.w = f2bf(s.w);
        b.x = f2bf(s.x + p.x); b.y = f2bf(s.y + p.y);
        b.z = f2bf(s.z + p.z); b.w = f2bf(s.w + p.w);
        ((ushort4*)s_bf)[i] = a;
        ((ushort4*)q_bf)[i] = b;
        return;
    }

    // ---- weight transpose: W [K,N] fp32 -> Wt [N,K] bf16 ----
    const float* W; ushort* Wt; int K, N, bx, by;
    if (bid < 64)       { W = Wv;    Wt = Wv_t;    K = 256;  N = 256;  bx = bid % 8;         by = bid / 8; }
    else if (bid < 128) { W = Woff;  Wt = Woff_t;  K = 256;  N = 256;  bx = (bid-64) % 8;    by = (bid-64) / 8; }
    else if (bid < 160) { W = Wattn; Wt = Wattn_t; K = 256;  N = 128;  bx = (bid-128) % 4;   by = (bid-128) / 4; }
    else if (bid < 224) { W = Wout;  Wt = Wout_t;  K = 256;  N = 256;  bx = (bid-160) % 8;   by = (bid-160) / 8; }
    else if (bid < 480) { W = W1;    Wt = W1_t;    K = 256;  N = 1024; bx = (bid-224) % 32;  by = (bid-224) / 32; }
    else                { W = W2;    Wt = W2_t;    K = 1024; N = 256;  bx = (bid-480) % 8;   by = (bid-480) / 8; }

    const int tx = tid & 31;
    const int ty = tid >> 5;
    for (int i = ty; i < 32; i += 8)
        tile[i][tx] = W[(size_t)(by * 32 + i) * N + bx * 32 + tx];
    __syncthreads();
    for (int i = ty; i < 32; i += 8)
        Wt[(size_t)(bx * 32 + i) * K + by * 32 + tx] = f2bf(tile[tx][i]);
}

// ---------------------------------------------------------------------------
// MFMA GEMM: C[M,N] = A[M,K](bf16) @ Bt[N,K](bf16)^T + bias, opt ReLU.
// 128x128 tile, BK=64, 4 waves, 4x4 16x16x32 tiles/wave.
// Double-buffered, counted vmcnt (prev tile's 8 loads only).
// XCD-chunked work mapping (bijective): hardware places block b on XCD b%8;
// remap so consecutive work items (same A row-panel, N-tile fast) share an
// XCD -> each A panel is fetched into ONE L2 instead of gridDim.x L2s.
// ---------------------------------------------------------------------------
#define BM 128
#define BN 128
#define BK 64

__global__ __launch_bounds__(256)
void mfma_gemm(const ushort* __restrict__ A, const ushort* __restrict__ Bt,
               const float* __restrict__ bias, float* __restrict__ Cf,
               ushort* __restrict__ Cb, int N, int K, int relu) {
    __shared__ ushort lA[2][BM * BK];   // 2 x 16 KiB
    __shared__ ushort lB[2][BN * BK];   // 2 x 16 KiB
    const int t = threadIdx.x;

    // bijective XCD-chunk swizzle (m204 form; works for nwg % 8 != 0 too)
    const int nt   = gridDim.x;
    const int nwg  = nt * gridDim.y;
    const int flat = blockIdx.y * nt + blockIdx.x;
    const int xc   = flat & 7;
    const int sl   = flat >> 3;
    const int q8   = nwg >> 3;
    const int rm8  = nwg & 7;
    const int wi   = (xc < rm8 ? xc * (q8 + 1) : rm8 * (q8 + 1) + (xc - rm8) * q8) + sl;
    const int col0 = (wi % nt) * BN;
    const int row0 = (wi / nt) * BM;

    const int w    = t >> 6;
    const int lr   = t & 15;
    const int quad = (t >> 4) & 3;
    const int wm   = (w >> 1) * 64;
    const int wn   = (w & 1) * 64;

    f32x4 acc[4][4];
    #pragma unroll
    for (int i = 0; i < 4; ++i)
        #pragma unroll
        for (int j = 0; j < 4; ++j)
            acc[i][j] = (f32x4){0.f, 0.f, 0.f, 0.f};

    const int sr = t >> 3;
    const int sc = (t & 7) * 8;
    const size_t aoff = (size_t)(row0 + sr) * K + sc;
    const size_t boff = (size_t)(col0 + sr) * K + sc;
    const int wb = w * 1024;

    auto stage = [&](int buf, int k0) {
        char* la = (char*)lA[buf] + wb;
        char* lb = (char*)lB[buf] + wb;
        #pragma unroll
        for (int g = 0; g < 4; ++g) {
            gload_lds16(A  + aoff + k0 + (size_t)g * 32 * K, la + g * 4096);
            gload_lds16(Bt + boff + k0 + (size_t)g * 32 * K, lb + g * 4096);
        }
    };

    stage(0, 0);                       // 8 loads in flight
    int cur = 0;
    for (int k0 = 0; k0 < K; k0 += BK) {
        if (k0 + BK < K) {
            stage(cur ^ 1, k0 + BK);   // +8 loads (16 in flight)
            asm volatile("s_waitcnt vmcnt(8)" ::: "memory");  // prev tile landed
        } else {
            asm volatile("s_waitcnt vmcnt(0)" ::: "memory");  // final tile
        }
        wg_barrier();                  // all waves' cur-tile stages visible
        const ushort* pA = lA[cur];
        const ushort* pB = lB[cur];
        #pragma unroll
        for (int kk = 0; kk < 2; ++kk) {
            short8 af[4], bfr[4];
            #pragma unroll
            for (int i = 0; i < 4; ++i)
                af[i] = *(const short8*)(pA + (wm + i * 16 + lr) * BK + kk * 32 + quad * 8);
            #pragma unroll
            for (int j = 0; j < 4; ++j)
                bfr[j] = *(const short8*)(pB + (wn + j * 16 + lr) * BK + kk * 32 + quad * 8);
            #pragma unroll
            for (int i = 0; i < 4; ++i)
                #pragma unroll
                for (int j = 0; j < 4; ++j)
                    acc[i][j] = __builtin_amdgcn_mfma_f32_16x16x32_bf16(af[i], bfr[j], acc[i][j], 0, 0, 0);
        }
        wg_barrier();                  // cur fully read before it is re-staged
        cur ^= 1;
    }

    #pragma unroll
    for (int j = 0; j < 4; ++j) {
        const int col = col0 + wn + j * 16 + lr;
        const float bb = bias ? bias[col] : 0.f;
        #pragma unroll
        for (int i = 0; i < 4; ++i) {
            const int rbase = row0 + wm + i * 16 + quad * 4;
            #pragma unroll
            for (int r = 0; r < 4; ++r) {
                float v = acc[i][j][r] + bb;
                if (relu) v = fmaxf(v, 0.f);
                if (Cf) Cf[(size_t)(rbase + r) * N + col] = v;
                else    Cb[(size_t)(rbase + r) * N + col] = f2bf(v);
            }
        }
    }
}

// ---------------------------------------------------------------------------
// Fused softmax + deformable bilinear sampling.
// 2 queries/block, 128 threads/query, scalar-FMA phase 2, XCD swizzle.
// LDS layout: row = tq*128 + p*8 + (h ^ (p&7)) — in-wave phase-2 reads of
// s_addr/s_w hit 4 distinct bank quads (conflict-free ds_read_b128); the
// XOR folds to one v_xor per p (shift-commutes into the byte offset).
// s_addr and s_w share one blob so both reads use the same vaddr + imm.
// ---------------------------------------------------------------------------
__global__ __launch_bounds__(256)
void msda_sample(const ushort* __restrict__ value, const float* __restrict__ comb,
                 const float* __restrict__ b_off, const float* __restrict__ b_attn,
                 const float* __restrict__ refp, ushort* __restrict__ out) {
    __shared__ int s_blob[2048];            // [0,1024): addr  [1024,2048): weights
    int*   s_addr = s_blob;
    float* s_w    = (float*)(s_blob + 1024);

    const int t   = threadIdx.x;
    const int tq  = t >> 7;          // 0..1
    const int u   = t & 127;
    // bijective XCD swizzle: 21760 blocks = 8 XCDs x 2720 contiguous
    const int bid = blockIdx.x;
    const int swz = (bid & 7) * (NQ_ / 2 / 8) + (bid >> 3);
    const int nq  = swz * 2 + tq;
    const int n   = nq / LQ_;

    // ---------------- phase 1: (h,p) ----------------
    {
        const int h = u >> 4;
        const int p = u & 15;
        const int l = p >> 2;

        const int starts[4] = {0, 4096, 5120, 5376};
        const int Wl = 64 >> l;

        // softmax over 16 points (p = low 4 lane bits -> shfl_xor group)
        float a = comb[(size_t)nq * 384 + 256 + u] + b_attn[u];
        float m = a;
        #pragma unroll
        for (int o = 8; o > 0; o >>= 1) m = fmaxf(m, __shfl_xor(m, o));
        float e = __expf(a - m);
        float s = e;
        #pragma unroll
        for (int o = 8; o > 0; o >>= 1) s += __shfl_xor(s, o);
        const float wgt = e / s;

        const float rx = refp[(size_t)nq * 8 + l * 2 + 0];
        const float ry = refp[(size_t)nq * 8 + l * 2 + 1];
        const float ox = comb[(size_t)nq * 384 + u * 2 + 0] + b_off[u * 2 + 0];
        const float oy = comb[(size_t)nq * 384 + u * 2 + 1] + b_off[u * 2 + 1];

        const float fw = (float)Wl;
        const float x  = (rx + ox / fw) * fw - 0.5f;
        const float y  = (ry + oy / fw) * fw - 0.5f;
        const float x0f = floorf(x), y0f = floorf(y);
        const int   x0 = (int)x0f, y0 = (int)y0f;
        const float wx1 = x - x0f, wy1 = y - y0f;
        const float wx0 = 1.f - wx1, wy0 = 1.f - wy1;

        const float xm0 = (x0 >= 0 && x0 < Wl) ? 1.f : 0.f;
        const float xm1 = (x0 + 1 >= 0 && x0 + 1 < Wl) ? 1.f : 0.f;
        const float ym0 = (y0 >= 0 && y0 < Wl) ? 1.f : 0.f;
        const float ym1 = (y0 + 1 >= 0 && y0 + 1 < Wl) ? 1.f : 0.f;

        const int x0c = min(max(x0, 0), Wl - 1);
        const int x1c = min(max(x0 + 1, 0), Wl - 1);
        const int y0c = min(max(y0, 0), Wl - 1);
        const int y1c = min(max(y0 + 1, 0), Wl - 1);

        // BYTE offsets: value row = 256 bf16 = 512 B; head offset = h*64 B
        const int base = (n * LQ_ + starts[l]) * 512 + h * 64;
        const int idx  = (tq << 7) + (p << 3) + (h ^ (p & 7));   // swizzled row
        s_addr[idx * 4 + 0] = base + (y0c * Wl + x0c) * 512;
        s_addr[idx * 4 + 1] = base + (y0c * Wl + x1c) * 512;
        s_addr[idx * 4 + 2] = base + (y1c * Wl + x0c) * 512;
        s_addr[idx * 4 + 3] = base + (y1c * Wl + x1c) * 512;
        s_w[idx * 4 + 0] = wgt * wy0 * wx0 * ym0 * xm0;
        s_w[idx * 4 + 1] = wgt * wy0 * wx1 * ym0 * xm1;
        s_w[idx * 4 + 2] = wgt * wy1 * wx0 * ym1 * xm0;
        s_w[idx * 4 + 3] = wgt * wy1 * wx1 * ym1 * xm1;
    }
    __syncthreads();

    // ---------------- phase 2: (h,d2) ----------------
    {
        const int h   = u >> 4;
        const int d2  = u & 15;                  // uint index: elems 2*d2, 2*d2+1
        const int tqb = tq << 7;
        const uint dby = (uint)(d2 * 4);         // byte offset of this uint in row
        const char* vbase = (const char*)value;

        float acc0 = 0.f, acc1 = 0.f;
        #pragma unroll 8
        for (int p = 0; p < 16; ++p) {
            const int row = tqb + (p << 3) + (h ^ (p & 7));
            const int*   ap = s_addr + row * 4;
            const float* wp = s_w    + row * 4;
            #pragma unroll
            for (int c = 0; c < 4; ++c) {
                const uint v = *(const uint*)(vbase + ((uint)ap[c] + dby));
                const float w = wp[c];
                union { uint u; float f; } lo, hi;
                lo.u = v << 16;            // bf16 lane 0 -> f32
                hi.u = v & 0xffff0000u;    // bf16 lane 1 -> f32
                acc0 = fmaf(lo.f, w, acc0);
                acc1 = fmaf(hi.f, w, acc1);
            }
        }
        const uint packed = (uint)f2bf(acc0) | ((uint)f2bf(acc1) << 16);
        ((uint*)out)[(size_t)nq * 128 + u] = packed;
    }
}

// ---------------------------------------------------------------------------
// x = LayerNorm(a + b); wave-per-row, float4 per lane, shuffle-only reduce.
// grid = NQ/4, block = 256 (4 waves = 4 rows).
// ---------------------------------------------------------------------------
__global__ __launch_bounds__(256)
void add_ln(const float* __restrict__ a, const float* __restrict__ b,
            const float* __restrict__ g, const float* __restrict__ be,
            float* __restrict__ xf, ushort* __restrict__ xb) {
    const int row  = blockIdx.x * 4 + (threadIdx.x >> 6);
    const int lane = threadIdx.x & 63;
    const size_t base = (size_t)row * 256 + lane * 4;

    const float4 av = *(const float4*)(a + base);
    const float4 bv = *(const float4*)(b + base);
    float4 x;
    x.x = av.x + bv.x; x.y = av.y + bv.y; x.z = av.z + bv.z; x.w = av.w + bv.w;

    float s = x.x + x.y + x.z + x.w;
    #pragma unroll
    for (int o = 32; o > 0; o >>= 1) s += __shfl_xor(s, o);
    const float mu = s * (1.f / 256.f);

    float4 dx;
    dx.x = x.x - mu; dx.y = x.y - mu; dx.z = x.z - mu; dx.w = x.w - mu;
    float vv = dx.x * dx.x + dx.y * dx.y + dx.z * dx.z + dx.w * dx.w;
    #pragma unroll
    for (int o = 32; o > 0; o >>= 1) vv += __shfl_xor(vv, o);
    const float rstd = rsqrtf(vv * (1.f / 256.f) + 1e-5f);

    const float4 gv  = *(const float4*)(g  + lane * 4);
    const float4 bev = *(const float4*)(be + lane * 4);
    float4 y;
    y.x = dx.x * rstd * gv.x + bev.x;
    y.y = dx.y * rstd * gv.y + bev.y;
    y.z = dx.z * rstd * gv.z + bev.z;
    y.w = dx.w * rstd * gv.w + bev.w;

    *(float4*)(xf + base) = y;
    if (xb) {
        ushort4 yb;
        yb.x = f2bf(y.x); yb.y = f2bf(y.y); yb.z = f2bf(y.z); yb.w = f2bf(y.w);
        *(ushort4*)(xb + base) = yb;
    }
}

// ---------------------------------------------------------------------------
extern "C" void kernel_launch(void* const* d_in, const int* in_sizes, int n_in,
                              void* d_out, int out_size, void* d_ws, size_t ws_size,
                              hipStream_t stream) {
    const float* src     = (const float*)d_in[0];
    const float* pos     = (const float*)d_in[1];
    const float* refp    = (const float*)d_in[2];
    const float* W_value = (const float*)d_in[4];
    const float* b_value = (const float*)d_in[5];
    const float* W_off   = (const float*)d_in[6];
    const float* b_off   = (const float*)d_in[7];
    const float* W_attn  = (const float*)d_in[8];
    const float* b_attn  = (const float*)d_in[9];
    const float* W_out   = (const float*)d_in[10];
    const float* b_out   = (const float*)d_in[11];
    const float* ln1g    = (const float*)d_in[12];
    const float* ln1b    = (const float*)d_in[13];
    const float* W1      = (const float*)d_in[14];
    const float* b1      = (const float*)d_in[15];
    const float* W2      = (const float*)d_in[16];
    const float* b2      = (const float*)d_in[17];
    const float* ln2g    = (const float*)d_in[18];
    const float* ln2b    = (const float*)d_in[19];
    float* out = (float*)d_out;
    char*  ws  = (char*)d_ws;

    // ---- workspace layout (byte offsets) ----
    const size_t SZ_BF = (size_t)NQ_ * 256 * 2;   // 22,282,240
    const size_t SZ_F  = (size_t)NQ_ * 256 * 4;   // 44,564,480
    ushort* s_bf    = (ushort*)(ws);                            // [0, 22.28M)
    ushort* q_bf    = (ushort*)(ws + SZ_BF);                    // [22.28M, 44.56M)
    ushort* val_bf  = (ushort*)(ws + 2 * SZ_BF);                // [44.56M, 66.85M)
    float*  comb    = (float*) (ws + 3 * SZ_BF);                // [66.85M, 133.69M)  NQ x 384 fp32
    ushort* samp_bf = (ushort*)(ws + 4 * SZ_BF + SZ_F);         // [133.69M, 155.98M)
    ushort* h_bf    = (ushort*)(ws);                            // overlays [0, 89.13M) — s/q/val/comb-head dead
    ushort* x_bf    = (ushort*)(ws + 3 * SZ_BF + SZ_F);         // overlays comb tail (dead after sampling)
    char*   wbase   = ws + 5 * SZ_BF + SZ_F;                    // 155.98M
    ushort* Wv_t    = (ushort*)(wbase);
    ushort* Woff_t  = (ushort*)(wbase + 131072);   // contiguous with Wattn_t -> one [384][256] Bt
    ushort* Wattn_t = (ushort*)(wbase + 262144);
    ushort* Wout_t  = (ushort*)(wbase + 327680);
    ushort* W1_t    = (ushort*)(wbase + 458752);
    ushort* W2_t    = (ushort*)(wbase + 983040);
    char*   fbase   = wbase + 1507328;
    float*  src2    = (float*)(fbase);                          // also ffn2
    float*  xf      = (float*)(fbase + SZ_F);

    // 0. fused prep: bf16 inputs + all weight transposes (one launch)
    prep<<<dim3(TPREP_ + (NQ_ * 256 / 4) / 256), 256, 0, stream>>>(
        src, pos, s_bf, q_bf, W_value, W_off, W_attn, W_out, W1, W2,
        Wv_t, Woff_t, Wattn_t, Wout_t, W1_t, W2_t);

    const int MT = NQ_ / BM;  // 340

    // 1. value = src @ Wv + bv  (bf16 out)
    mfma_gemm<<<dim3(2, MT), 256, 0, stream>>>(s_bf, Wv_t, b_value, nullptr, val_bf, 256, 256, 0);
    // 2. comb = q @ [Woff|Wattn]  (fp32, N=384, biases folded into msda_sample)
    mfma_gemm<<<dim3(3, MT), 256, 0, stream>>>(q_bf, Woff_t, nullptr, comb, nullptr, 384, 256, 0);
    // 3+4. fused softmax + sampling -> bf16
    msda_sample<<<dim3(NQ_ / 2), 256, 0, stream>>>(val_bf, comb, b_off, b_attn, refp, samp_bf);
    // 5. src2 = sampled @ Wout + bout (fp32)
    mfma_gemm<<<dim3(2, MT), 256, 0, stream>>>(samp_bf, Wout_t, b_out, src2, nullptr, 256, 256, 0);
    // 6. x = LN(src + src2) -> fp32 + bf16
    add_ln<<<dim3(NQ_ / 4), 256, 0, stream>>>(src, src2, ln1g, ln1b, xf, x_bf);
    // 7. h = relu(x @ W1 + b1) -> bf16
    mfma_gemm<<<dim3(8, MT), 256, 0, stream>>>(x_bf, W1_t, b1, nullptr, h_bf, 1024, 256, 1);
    // 8. ffn2 = h @ W2 + b2 -> fp32 (overlays src2)
    mfma_gemm<<<dim3(2, MT), 256, 0, stream>>>(h_bf, W2_t, b2, src2, nullptr, 256, 1024, 0);
    // 9. out = LN(x + ffn2)
    add_ln<<<dim3(NQ_ / 4), 256, 0, stream>>>(xf, src2, ln2g, ln2b, out, nullptr);
}

// Round 6
// 440.030 us; speedup vs baseline: 1.2234x; 1.1085x over previous
//
#include <hip/hip_runtime.h>
#include <math.h>

#define LQ_ 5440
#define NB_ 8
#define NQ_ (NB_ * LQ_)   // 43520
#define D_  256
#define NH_ 8
#define HD_ 32

typedef __attribute__((ext_vector_type(8))) short short8;
typedef __attribute__((ext_vector_type(4))) float f32x4;

__device__ __forceinline__ ushort f2bf(float f) {
    union { float f; unsigned u; } v; v.f = f;
    unsigned u = v.u;
    unsigned r = (u + 0x7FFFu + ((u >> 16) & 1u)) >> 16;
    return (ushort)r;
}
__device__ __forceinline__ float bf2f(ushort u) {
    union { unsigned u; float f; } v; v.u = ((unsigned)u) << 16; return v.f;
}

// async global->LDS, 16 B per lane. LDS dest = wave-uniform base + lane*16.
__device__ __forceinline__ void gload_lds16(const void* g, void* l) {
    __builtin_amdgcn_global_load_lds(
        (const __attribute__((address_space(1))) void*)g,
        (__attribute__((address_space(3))) void*)l, 16, 0, 0);
}

// raw workgroup barrier, fenced so no memory op is scheduled across it.
__device__ __forceinline__ void wg_barrier() {
    __builtin_amdgcn_sched_barrier(0);
    __builtin_amdgcn_s_barrier();
    __builtin_amdgcn_sched_barrier(0);
}

// ---------------------------------------------------------------------------
// Fused prep: ONE launch for bf16 input casts + all 6 weight transposes.
// Blocks [0,736): transposes; blocks [736, 736+10880): make_bf.
// ---------------------------------------------------------------------------
#define TPREP_ 736

__global__ __launch_bounds__(256)
void prep(const float* __restrict__ src, const float* __restrict__ pos,
          ushort* __restrict__ s_bf, ushort* __restrict__ q_bf,
          const float* __restrict__ Wv, const float* __restrict__ Woff,
          const float* __restrict__ Wattn, const float* __restrict__ Wout,
          const float* __restrict__ W1, const float* __restrict__ W2,
          ushort* __restrict__ Wv_t, ushort* __restrict__ Woff_t,
          ushort* __restrict__ Wattn_t, ushort* __restrict__ Wout_t,
          ushort* __restrict__ W1_t, ushort* __restrict__ W2_t) {
    __shared__ float tile[32][33];
    const int bid = blockIdx.x;
    const int tid = threadIdx.x;

    if (bid >= TPREP_) {
        // ---- bf16 inputs: s_bf = bf16(src), q_bf = bf16(src+pos) ----
        const int i = (bid - TPREP_) * 256 + tid;
        const float4 s = ((const float4*)src)[i];
        const float4 p = ((const float4*)pos)[i];
        ushort4 a, b;
        a.x = f2bf(s.x); a.y = f2bf(s.y); a.z = f2bf(s.z); a.w = f2bf(s.w);
        b.x = f2bf(s.x + p.x); b.y = f2bf(s.y + p.y);
        b.z = f2bf(s.z + p.z); b.w = f2bf(s.w + p.w);
        ((ushort4*)s_bf)[i] = a;
        ((ushort4*)q_bf)[i] = b;
        return;
    }

    // ---- weight transpose: W [K,N] fp32 -> Wt [N,K] bf16 ----
    const float* W; ushort* Wt; int K, N, bx, by;
    if (bid < 64)       { W = Wv;    Wt = Wv_t;    K = 256;  N = 256;  bx = bid % 8;         by = bid / 8; }
    else if (bid < 128) { W = Woff;  Wt = Woff_t;  K = 256;  N = 256;  bx = (bid-64) % 8;    by = (bid-64) / 8; }
    else if (bid < 160) { W = Wattn; Wt = Wattn_t; K = 256;  N = 128;  bx = (bid-128) % 4;   by = (bid-128) / 4; }
    else if (bid < 224) { W = Wout;  Wt = Wout_t;  K = 256;  N = 256;  bx = (bid-160) % 8;   by = (bid-160) / 8; }
    else if (bid < 480) { W = W1;    Wt = W1_t;    K = 256;  N = 1024; bx = (bid-224) % 32;  by = (bid-224) / 32; }
    else                { W = W2;    Wt = W2_t;    K = 1024; N = 256;  bx = (bid-480) % 8;   by = (bid-480) / 8; }

    const int tx = tid & 31;
    const int ty = tid >> 5;
    for (int i = ty; i < 32; i += 8)
        tile[i][tx] = W[(size_t)(by * 32 + i) * N + bx * 32 + tx];
    __syncthreads();
    for (int i = ty; i < 32; i += 8)
        Wt[(size_t)(bx * 32 + i) * K + by * 32 + tx] = f2bf(tile[tx][i]);
}

// ---------------------------------------------------------------------------
// Shared MFMA GEMM body: C[M,N] = A[M,K](bf16) @ Bt[N,K](bf16)^T + bias.
// 128x128 tile, BK=64, 4 waves, 4x4 16x16x32 tiles/wave.
// Double-buffered, counted vmcnt (waits only the PREVIOUS tile's 8 loads;
// fresh 8 stay in flight across the barrier).
// ---------------------------------------------------------------------------
#define BM 128
#define BN 128
#define BK 64

__device__ __forceinline__ void gemm_body(
    ushort* __restrict__ lAb, ushort* __restrict__ lBb,   // [2][BM*BK] each
    const ushort* __restrict__ A, const ushort* __restrict__ Bt,
    const float* __restrict__ bias, float* __restrict__ Cf,
    ushort* __restrict__ Cb, int N, int K, int relu, int col0, int row0) {
    const int t    = threadIdx.x;
    const int w    = t >> 6;
    const int lr   = t & 15;
    const int quad = (t >> 4) & 3;
    const int wm   = (w >> 1) * 64;
    const int wn   = (w & 1) * 64;

    f32x4 acc[4][4];
    #pragma unroll
    for (int i = 0; i < 4; ++i)
        #pragma unroll
        for (int j = 0; j < 4; ++j)
            acc[i][j] = (f32x4){0.f, 0.f, 0.f, 0.f};

    const int sr = t >> 3;
    const int sc = (t & 7) * 8;
    const size_t aoff = (size_t)(row0 + sr) * K + sc;
    const size_t boff = (size_t)(col0 + sr) * K + sc;
    const int wb = w * 1024;

    auto stage = [&](int buf, int k0) {
        char* la = (char*)(lAb + buf * (BM * BK)) + wb;
        char* lb = (char*)(lBb + buf * (BN * BK)) + wb;
        #pragma unroll
        for (int g = 0; g < 4; ++g) {
            gload_lds16(A  + aoff + k0 + (size_t)g * 32 * K, la + g * 4096);
            gload_lds16(Bt + boff + k0 + (size_t)g * 32 * K, lb + g * 4096);
        }
    };

    stage(0, 0);                       // 8 loads in flight
    int cur = 0;
    for (int k0 = 0; k0 < K; k0 += BK) {
        if (k0 + BK < K) {
            stage(cur ^ 1, k0 + BK);   // +8 loads (16 in flight)
            asm volatile("s_waitcnt vmcnt(8)" ::: "memory");  // prev tile landed
        } else {
            asm volatile("s_waitcnt vmcnt(0)" ::: "memory");  // final tile
        }
        wg_barrier();                  // all waves' cur-tile stages visible
        const ushort* pA = lAb + cur * (BM * BK);
        const ushort* pB = lBb + cur * (BN * BK);
        #pragma unroll
        for (int kk = 0; kk < 2; ++kk) {
            short8 af[4], bfr[4];
            #pragma unroll
            for (int i = 0; i < 4; ++i)
                af[i] = *(const short8*)(pA + (wm + i * 16 + lr) * BK + kk * 32 + quad * 8);
            #pragma unroll
            for (int j = 0; j < 4; ++j)
                bfr[j] = *(const short8*)(pB + (wn + j * 16 + lr) * BK + kk * 32 + quad * 8);
            #pragma unroll
            for (int i = 0; i < 4; ++i)
                #pragma unroll
                for (int j = 0; j < 4; ++j)
                    acc[i][j] = __builtin_amdgcn_mfma_f32_16x16x32_bf16(af[i], bfr[j], acc[i][j], 0, 0, 0);
        }
        wg_barrier();                  // cur fully read before it is re-staged
        cur ^= 1;
    }

    #pragma unroll
    for (int j = 0; j < 4; ++j) {
        const int col = col0 + wn + j * 16 + lr;
        const float bb = bias ? bias[col] : 0.f;
        #pragma unroll
        for (int i = 0; i < 4; ++i) {
            const int rbase = row0 + wm + i * 16 + quad * 4;
            #pragma unroll
            for (int r = 0; r < 4; ++r) {
                float v = acc[i][j][r] + bb;
                if (relu) v = fmaxf(v, 0.f);
                if (Cf) Cf[(size_t)(rbase + r) * N + col] = v;
                else    Cb[(size_t)(rbase + r) * N + col] = f2bf(v);
            }
        }
    }
}

// generic GEMM: grid (N/BN, M/BM), XCD-chunked bijective mapping.
__global__ __launch_bounds__(256)
void mfma_gemm(const ushort* __restrict__ A, const ushort* __restrict__ Bt,
               const float* __restrict__ bias, float* __restrict__ Cf,
               ushort* __restrict__ Cb, int N, int K, int relu) {
    __shared__ ushort lA[2][BM * BK];
    __shared__ ushort lB[2][BN * BK];
    const int nt   = gridDim.x;
    const int nwg  = nt * gridDim.y;
    const int flat = blockIdx.y * nt + blockIdx.x;
    const int xc   = flat & 7;
    const int sl   = flat >> 3;
    const int q8   = nwg >> 3;
    const int rm8  = nwg & 7;
    const int wi   = (xc < rm8 ? xc * (q8 + 1) : rm8 * (q8 + 1) + (xc - rm8) * q8) + sl;
    gemm_body(&lA[0][0], &lB[0][0], A, Bt, bias, Cf, Cb, N, K, relu,
              (wi % nt) * BN, (wi / nt) * BM);
}

// fused value+comb GEMM: grid 1700 = 340 row panels x (2 value + 3 comb cols).
// Same M, same K; per-panel both A arrays stream through one XCD's L2.
__global__ __launch_bounds__(256)
void gemm_vc(const ushort* __restrict__ s_bf, const ushort* __restrict__ q_bf,
             const ushort* __restrict__ Wv_t, const ushort* __restrict__ Woff_t,
             const float* __restrict__ b_value,
             ushort* __restrict__ val_bf, ushort* __restrict__ comb_bf) {
    __shared__ ushort lA[2][BM * BK];
    __shared__ ushort lB[2][BN * BK];
    const int nwg  = gridDim.x;         // 1700
    const int flat = blockIdx.x;
    const int xc   = flat & 7;
    const int sl   = flat >> 3;
    const int q8   = nwg >> 3;
    const int rm8  = nwg & 7;
    const int wi   = (xc < rm8 ? xc * (q8 + 1) : rm8 * (q8 + 1) + (xc - rm8) * q8) + sl;
    const int ci   = wi % 5;
    const int row0 = (wi / 5) * BM;
    if (ci < 2)
        gemm_body(&lA[0][0], &lB[0][0], s_bf, Wv_t, b_value, nullptr, val_bf,
                  256, 256, 0, ci * BN, row0);
    else
        gemm_body(&lA[0][0], &lB[0][0], q_bf, Woff_t, nullptr, nullptr, comb_bf,
                  384, 256, 0, (ci - 2) * BN, row0);
}

// ---------------------------------------------------------------------------
// Fused softmax + deformable bilinear sampling.  (round-4 proven structure:
// 2 queries/block, 128 threads/query, scalar FMA, XCD swizzle, contiguous
// LDS rows -> single-base ds_reads with immediate offsets.)
// comb is now bf16 (NQ x 384 = [offsets(256) | logits(128)]).
// ---------------------------------------------------------------------------
__global__ __launch_bounds__(256)
void msda_sample(const ushort* __restrict__ value, const ushort* __restrict__ comb,
                 const float* __restrict__ b_off, const float* __restrict__ b_attn,
                 const float* __restrict__ refp, ushort* __restrict__ out) {
    __shared__ int   s_addr[256][4];   // byte offsets into value (4 KiB)
    __shared__ float s_w[256][4];      // folded weights (4 KiB)

    const int t   = threadIdx.x;
    const int tq  = t >> 7;          // 0..1
    const int u   = t & 127;
    // bijective XCD swizzle: 21760 blocks = 8 XCDs x 2720 contiguous
    const int bid = blockIdx.x;
    const int swz = (bid & 7) * (NQ_ / 2 / 8) + (bid >> 3);
    const int nq  = swz * 2 + tq;
    const int n   = nq / LQ_;

    // ---------------- phase 1: (h,p) ----------------
    {
        const int h = u >> 4;
        const int p = u & 15;
        const int l = p >> 2;

        const int starts[4] = {0, 4096, 5120, 5376};
        const int Wl = 64 >> l;

        // softmax over 16 points (p = low 4 lane bits -> shfl_xor group)
        float a = bf2f(comb[(size_t)nq * 384 + 256 + u]) + b_attn[u];
        float m = a;
        #pragma unroll
        for (int o = 8; o > 0; o >>= 1) m = fmaxf(m, __shfl_xor(m, o));
        float e = __expf(a - m);
        float s = e;
        #pragma unroll
        for (int o = 8; o > 0; o >>= 1) s += __shfl_xor(s, o);
        const float wgt = e / s;

        const float rx = refp[(size_t)nq * 8 + l * 2 + 0];
        const float ry = refp[(size_t)nq * 8 + l * 2 + 1];
        const uint  opk = *(const uint*)(comb + (size_t)nq * 384 + u * 2);
        const float ox = bf2f((ushort)(opk & 0xffffu))  + b_off[u * 2 + 0];
        const float oy = bf2f((ushort)(opk >> 16))      + b_off[u * 2 + 1];

        const float fw = (float)Wl;
        const float x  = (rx + ox / fw) * fw - 0.5f;
        const float y  = (ry + oy / fw) * fw - 0.5f;
        const float x0f = floorf(x), y0f = floorf(y);
        const int   x0 = (int)x0f, y0 = (int)y0f;
        const float wx1 = x - x0f, wy1 = y - y0f;
        const float wx0 = 1.f - wx1, wy0 = 1.f - wy1;

        const float xm0 = (x0 >= 0 && x0 < Wl) ? 1.f : 0.f;
        const float xm1 = (x0 + 1 >= 0 && x0 + 1 < Wl) ? 1.f : 0.f;
        const float ym0 = (y0 >= 0 && y0 < Wl) ? 1.f : 0.f;
        const float ym1 = (y0 + 1 >= 0 && y0 + 1 < Wl) ? 1.f : 0.f;

        const int x0c = min(max(x0, 0), Wl - 1);
        const int x1c = min(max(x0 + 1, 0), Wl - 1);
        const int y0c = min(max(y0, 0), Wl - 1);
        const int y1c = min(max(y0 + 1, 0), Wl - 1);

        // BYTE offsets: value row = 256 bf16 = 512 B; head offset = h*64 B
        const int base = (n * LQ_ + starts[l]) * 512 + h * 64;
        s_addr[t][0] = base + (y0c * Wl + x0c) * 512;
        s_addr[t][1] = base + (y0c * Wl + x1c) * 512;
        s_addr[t][2] = base + (y1c * Wl + x0c) * 512;
        s_addr[t][3] = base + (y1c * Wl + x1c) * 512;
        s_w[t][0] = wgt * wy0 * wx0 * ym0 * xm0;
        s_w[t][1] = wgt * wy0 * wx1 * ym0 * xm1;
        s_w[t][2] = wgt * wy1 * wx0 * ym1 * xm0;
        s_w[t][3] = wgt * wy1 * wx1 * ym1 * xm1;
    }
    __syncthreads();

    // ---------------- phase 2: (h,d2) ----------------
    {
        const int h   = u >> 4;
        const int d2  = u & 15;                  // uint index: elems 2*d2, 2*d2+1
        const int sb  = tq * 128 + h * 16;
        const uint dby = (uint)(d2 * 4);         // byte offset of this uint in row
        const char* vbase = (const char*)value;

        float acc0 = 0.f, acc1 = 0.f;
        #pragma unroll 8
        for (int p = 0; p < 16; ++p) {
            const int*   ap = s_addr[sb + p];
            const float* wp = s_w[sb + p];
            #pragma unroll
            for (int c = 0; c < 4; ++c) {
                const uint v = *(const uint*)(vbase + ((uint)ap[c] + dby));
                const float w = wp[c];
                union { uint u; float f; } lo, hi;
                lo.u = v << 16;            // bf16 lane 0 -> f32
                hi.u = v & 0xffff0000u;    // bf16 lane 1 -> f32
                acc0 = fmaf(lo.f, w, acc0);
                acc1 = fmaf(hi.f, w, acc1);
            }
        }
        const uint packed = (uint)f2bf(acc0) | ((uint)f2bf(acc1) << 16);
        ((uint*)out)[(size_t)nq * 128 + u] = packed;
    }
}

// ---------------------------------------------------------------------------
// x = LayerNorm(a + b); wave-per-row, float4 per lane, shuffle-only reduce.
// grid = NQ/4, block = 256 (4 waves = 4 rows).
// ---------------------------------------------------------------------------
__global__ __launch_bounds__(256)
void add_ln(const float* __restrict__ a, const float* __restrict__ b,
            const float* __restrict__ g, const float* __restrict__ be,
            float* __restrict__ xf, ushort* __restrict__ xb) {
    const int row  = blockIdx.x * 4 + (threadIdx.x >> 6);
    const int lane = threadIdx.x & 63;
    const size_t base = (size_t)row * 256 + lane * 4;

    const float4 av = *(const float4*)(a + base);
    const float4 bv = *(const float4*)(b + base);
    float4 x;
    x.x = av.x + bv.x; x.y = av.y + bv.y; x.z = av.z + bv.z; x.w = av.w + bv.w;

    float s = x.x + x.y + x.z + x.w;
    #pragma unroll
    for (int o = 32; o > 0; o >>= 1) s += __shfl_xor(s, o);
    const float mu = s * (1.f / 256.f);

    float4 dx;
    dx.x = x.x - mu; dx.y = x.y - mu; dx.z = x.z - mu; dx.w = x.w - mu;
    float vv = dx.x * dx.x + dx.y * dx.y + dx.z * dx.z + dx.w * dx.w;
    #pragma unroll
    for (int o = 32; o > 0; o >>= 1) vv += __shfl_xor(vv, o);
    const float rstd = rsqrtf(vv * (1.f / 256.f) + 1e-5f);

    const float4 gv  = *(const float4*)(g  + lane * 4);
    const float4 bev = *(const float4*)(be + lane * 4);
    float4 y;
    y.x = dx.x * rstd * gv.x + bev.x;
    y.y = dx.y * rstd * gv.y + bev.y;
    y.z = dx.z * rstd * gv.z + bev.z;
    y.w = dx.w * rstd * gv.w + bev.w;

    *(float4*)(xf + base) = y;
    if (xb) {
        ushort4 yb;
        yb.x = f2bf(y.x); yb.y = f2bf(y.y); yb.z = f2bf(y.z); yb.w = f2bf(y.w);
        *(ushort4*)(xb + base) = yb;
    }
}

// ---------------------------------------------------------------------------
extern "C" void kernel_launch(void* const* d_in, const int* in_sizes, int n_in,
                              void* d_out, int out_size, void* d_ws, size_t ws_size,
                              hipStream_t stream) {
    const float* src     = (const float*)d_in[0];
    const float* pos     = (const float*)d_in[1];
    const float* refp    = (const float*)d_in[2];
    const float* W_value = (const float*)d_in[4];
    const float* b_value = (const float*)d_in[5];
    const float* W_off   = (const float*)d_in[6];
    const float* b_off   = (const float*)d_in[7];
    const float* W_attn  = (const float*)d_in[8];
    const float* b_attn  = (const float*)d_in[9];
    const float* W_out   = (const float*)d_in[10];
    const float* b_out   = (const float*)d_in[11];
    const float* ln1g    = (const float*)d_in[12];
    const float* ln1b    = (const float*)d_in[13];
    const float* W1      = (const float*)d_in[14];
    const float* b1      = (const float*)d_in[15];
    const float* W2      = (const float*)d_in[16];
    const float* b2      = (const float*)d_in[17];
    const float* ln2g    = (const float*)d_in[18];
    const float* ln2b    = (const float*)d_in[19];
    float* out = (float*)d_out;
    char*  ws  = (char*)d_ws;

    // ---- workspace layout (byte offsets) ----
    const size_t SZ_BF  = (size_t)NQ_ * 256 * 2;    // 22,282,240
    const size_t SZ_CB  = (size_t)NQ_ * 384 * 2;    // 33,423,360 (comb bf16)
    const size_t SZ_F   = (size_t)NQ_ * 256 * 4;    // 44,564,480
    ushort* s_bf    = (ushort*)(ws);                             // [0, 22.3M)
    ushort* q_bf    = (ushort*)(ws + SZ_BF);                     // [22.3M, 44.6M)
    ushort* val_bf  = (ushort*)(ws + 2 * SZ_BF);                 // [44.6M, 66.8M)
    ushort* comb    = (ushort*)(ws + 3 * SZ_BF);                 // [66.8M, 100.3M)
    ushort* samp_bf = (ushort*)(ws + 3 * SZ_BF + SZ_CB);         // [100.3M, 122.6M)
    ushort* h_bf    = (ushort*)(ws);                             // overlays [0, 89.1M): s/q/val/comb dead at FFN1
    ushort* x_bf    = (ushort*)(ws + 3 * SZ_BF + SZ_CB);         // overlays samp_bf (dead after Wout GEMM)
    char*   wbase   = ws + 3 * SZ_BF + SZ_CB + SZ_BF;            // 122.6M
    ushort* Wv_t    = (ushort*)(wbase);
    ushort* Woff_t  = (ushort*)(wbase + 131072);   // contiguous with Wattn_t -> one [384][256] Bt
    ushort* Wattn_t = (ushort*)(wbase + 262144);
    ushort* Wout_t  = (ushort*)(wbase + 327680);
    ushort* W1_t    = (ushort*)(wbase + 458752);
    ushort* W2_t    = (ushort*)(wbase + 983040);
    char*   fbase   = wbase + 1507328;
    float*  src2    = (float*)(fbase);                           // also ffn2
    float*  xf      = (float*)(fbase + SZ_F);

    // 0. fused prep: bf16 inputs + all weight transposes (one launch)
    prep<<<dim3(TPREP_ + (NQ_ * 256 / 4) / 256), 256, 0, stream>>>(
        src, pos, s_bf, q_bf, W_value, W_off, W_attn, W_out, W1, W2,
        Wv_t, Woff_t, Wattn_t, Wout_t, W1_t, W2_t);

    const int MT = NQ_ / BM;  // 340

    // 1. fused: value = src @ Wv + bv (bf16), comb = q @ [Woff|Wattn] (bf16)
    gemm_vc<<<dim3(5 * MT), 256, 0, stream>>>(s_bf, q_bf, Wv_t, Woff_t, b_value, val_bf, comb);
    // 2+3. fused softmax + sampling -> bf16
    msda_sample<<<dim3(NQ_ / 2), 256, 0, stream>>>(val_bf, comb, b_off, b_attn, refp, samp_bf);
    // 4. src2 = sampled @ Wout + bout (fp32)
    mfma_gemm<<<dim3(2, MT), 256, 0, stream>>>(samp_bf, Wout_t, b_out, src2, nullptr, 256, 256, 0);
    // 5. x = LN(src + src2) -> fp32 + bf16
    add_ln<<<dim3(NQ_ / 4), 256, 0, stream>>>(src, src2, ln1g, ln1b, xf, x_bf);
    // 6. h = relu(x @ W1 + b1) -> bf16
    mfma_gemm<<<dim3(8, MT), 256, 0, stream>>>(x_bf, W1_t, b1, nullptr, h_bf, 1024, 256, 1);
    // 7. ffn2 = h @ W2 + b2 -> fp32 (overlays src2)
    mfma_gemm<<<dim3(2, MT), 256, 0, stream>>>(h_bf, W2_t, b2, src2, nullptr, 256, 1024, 0);
    // 8. out = LN(x + ffn2)
    add_ln<<<dim3(NQ_ / 4), 256, 0, stream>>>(xf, src2, ln2g, ln2b, out, nullptr);
}